// Round 20
// baseline (740.361 us; speedup 1.0000x reference)
//
#include <hip/hip_runtime.h>
#include <hip/hip_bf16.h>
#include <math.h>

// LSTM language model. Round 20: embed/xW prep FOLDED into the fused kernel
// (blocks 64..1087), overlapped with the recurrence via sc1 stores + per-(t,
// tile) ready flags (r6's proven producer protocol); recurrence polls the
// flag inside its existing h-poll round (no added serial latency). U-conv
// stays a tiny separate kernel (64KB LDS). Proj + recurrence = r17 bodies.
// ws layout (~58.8 MB):
//   xWb    [128][16][4096] f32      33,554,432 B @ 0
//   ub_hi  [256ct][32kt][64][8] f16  8,388,608 B @ 33,554,432
//   ub_lo   (same)                   8,388,608 B @ 41,943,040
//   hslots [129][hi 16384 | lo 16384] ushort = 8,454,144 B @ 50,331,648
//          slot t: elem(b,j) = (j>>5)*512 + (((j>>3)&3)*16+b)*8 + (j&7);
//          slot 0 zeroed (h0), rest poisoned 0xFFFF (fp16 NaN).
//   xwf    [128][8] u32 flags        4,096 B @ 58,785,792 (zeroed)

#define VOCAB 32000
#define EMBED 256
#define UNITS 1024
#define GATES 4096
#define BATCH 16
#define SEQ 128
#define NB 64        // persistent recurrence blocks
#define EMB_BLKS 1024

using s16x8 = __attribute__((ext_vector_type(8))) short;
using f16x8 = __attribute__((ext_vector_type(8))) _Float16;
using f32x4 = __attribute__((ext_vector_type(4))) float;

__device__ __forceinline__ unsigned short f16_bits(float x) {
    _Float16 h = (_Float16)x;                 // v_cvt_f16_f32, RNE
    return __builtin_bit_cast(unsigned short, h);
}
__device__ __forceinline__ float f16_f32(unsigned short b) {
    return (float)__builtin_bit_cast(_Float16, b);
}
__device__ __forceinline__ int swz_e(int r, int k) {
    return (r * 64 + k) ^ ((((r & 7) ^ ((r >> 2) & 7))) << 3);
}
__device__ __forceinline__ unsigned long long ld_u64(const unsigned long long* p) {
    return __hip_atomic_load(p, __ATOMIC_RELAXED, __HIP_MEMORY_SCOPE_AGENT);
}
__device__ __forceinline__ unsigned ld_u32(const unsigned* p) {
    return __hip_atomic_load(p, __ATOMIC_RELAXED, __HIP_MEMORY_SCOPE_AGENT);
}
__device__ __forceinline__ void st_u32(unsigned* p, unsigned v) {
    __hip_atomic_store(p, v, __ATOMIC_RELAXED, __HIP_MEMORY_SCOPE_AGENT);
}
__device__ __forceinline__ unsigned poison_u64(unsigned long long v) {
    return (unsigned)((unsigned)v == 0xFFFFFFFFu) |
           (unsigned)((unsigned)(v >> 32) == 0xFFFFFFFFu);
}

// ---------- K0: U [1024][4096] -> fragment-ordered fp16 hi/lo ----------
__global__ void __launch_bounds__(256) k_prep_u(
    const float* __restrict__ U,
    unsigned short* __restrict__ ub_hi,
    unsigned short* __restrict__ ub_lo) {
    __shared__ float lds_u[1024 * 16];     // [k][16 cols], 64 KB
    const int ct = blockIdx.x;             // 0..255
    const int tid = threadIdx.x;
    for (int k = tid; k < 1024; k += 256) {
        const float4* src = (const float4*)(U + (size_t)k * GATES + ct * 16);
        float4* dst = (float4*)(&lds_u[k * 16]);
        dst[0] = src[0]; dst[1] = src[1]; dst[2] = src[2]; dst[3] = src[3];
    }
    __syncthreads();
    const int lane = tid & 63;
    const int coll = lane & 15;
    const int kg = lane >> 4;
    for (int kt = (tid >> 6); kt < 32; kt += 4) {
        const int ks = kt * 32 + kg * 8;
        unsigned short h8[8], l8[8];
#pragma unroll
        for (int e = 0; e < 8; ++e) {
            float v = lds_u[(ks + e) * 16 + coll];
            unsigned short hb = f16_bits(v);
            h8[e] = hb;
            l8[e] = f16_bits(v - f16_f32(hb));
        }
        size_t o = (((size_t)ct * 32 + kt) * 64 + lane) * 8;
        *(s16x8*)(ub_hi + o) = *(const s16x8*)h8;
        *(s16x8*)(ub_lo + o) = *(const s16x8*)l8;
    }
}

// ---------- K2: FUSED, 512 threads (8 waves) -------------------------------
// blocks 0..63: recurrence.  64..1087: embed/xW (1 t x 512 cols, sc1 stores
// + ready flag).  1088..5087: projection 128x128, mt2-major.
__global__ void __launch_bounds__(512, 2) k_fused(
    const unsigned short* __restrict__ ub_hi,
    const unsigned short* __restrict__ ub_lo,
    float* __restrict__ xWb,
    unsigned short* __restrict__ hsl,
    unsigned* __restrict__ xwf,
    const int* __restrict__ inputs,
    const float* __restrict__ emb,
    const float* __restrict__ W,
    const float* __restrict__ bias,
    const float* __restrict__ Wc,
    const float* __restrict__ bc,
    float* __restrict__ out) {
    __shared__ __align__(16) char smem_raw[32768];
    const int tid  = threadIdx.x;
    const int lane = tid & 63;
    const int w    = tid >> 6;            // wave 0..7

    if (blockIdx.x < NB) {
        // ================= recurrence path =================
        __builtin_amdgcn_s_setprio(1);
        float (*zpart)[4][256] = (float (*)[4][256])smem_raw;  // [8][4][256] 32KB
        const int bid = blockIdx.x;
        const int j0  = bid * 16;

        const int b_own  = (tid >> 4) & 15;    // owners are tid<256
        const int jj_own = tid & 15;
        const int j_own  = j0 + jj_own;
        const int hb_e = ((j_own >> 5) * 512) + (((j_own >> 3) & 3) * 16 + b_own) * 8 + (j_own & 7);
        float c_own = 0.f;

        // preload U fragments (once): 4 gc-tiles x 4 kt per wave = 128 VGPR
        f16x8 Uh[4][4], Ul[4][4];
#pragma unroll
        for (int g = 0; g < 4; ++g)
#pragma unroll
            for (int q = 0; q < 4; ++q) {
                size_t o = (((size_t)(g * 64 + bid) * 32) + (w * 4 + q)) * 512 + lane * 8;
                Uh[g][q] = *(const f16x8*)(ub_hi + o);
                Ul[g][q] = *(const f16x8*)(ub_lo + o);
            }

        for (int t = 0; t < SEQ; ++t) {
            const unsigned long long* p64 =
                (const unsigned long long*)(hsl + (size_t)t * 32768);
            const unsigned* xwfp = xwf + t * 8;

            // ---- merged poll: h data + xW ready-flag in the same round ----
            union HU { unsigned long long q2[2]; f16x8 v; };
            HU hh[4], hl[4];
            while (true) {
                unsigned fl = ld_u32(&xwfp[lane & 7]);
                unsigned bad = (unsigned)(fl == 0u);
#pragma unroll
                for (int q = 0; q < 4; ++q) {
                    const size_t u = (size_t)(w * 4 + q) * 128 + lane * 2;
                    hh[q].q2[0] = ld_u64(p64 + u);
                    hh[q].q2[1] = ld_u64(p64 + u + 1);
                    hl[q].q2[0] = ld_u64(p64 + 4096 + u);
                    hl[q].q2[1] = ld_u64(p64 + 4097 + u);
                }
#pragma unroll
                for (int q = 0; q < 4; ++q)
                    bad |= poison_u64(hh[q].q2[0]) | poison_u64(hh[q].q2[1]) |
                           poison_u64(hl[q].q2[0]) | poison_u64(hl[q].q2[1]);
                if (__all((int)(bad == 0))) break;
                __builtin_amdgcn_s_sleep(8);
            }
            asm volatile("" ::: "memory");   // xw loads stay after the poll

            // xW gather (first touch after flag; L2 invalid at launch ->
            // coherent plain loads); consumed ~1us later, latency hidden
            float xw0 = 0.f, xw1 = 0.f, xw2 = 0.f, xw3 = 0.f;
            if (tid < 256) {
                const float* xwp = xWb + ((size_t)t * BATCH + b_own) * GATES + j_own;
                xw0 = xwp[0]; xw1 = xwp[UNITS]; xw2 = xwp[2 * UNITS]; xw3 = xwp[3 * UNITS];
            }

            f32x4 a0[4], a1[4], a2[4];
#pragma unroll
            for (int g = 0; g < 4; ++g) {
                a0[g] = (f32x4){0.f, 0.f, 0.f, 0.f};
                a1[g] = (f32x4){0.f, 0.f, 0.f, 0.f};
                a2[g] = (f32x4){0.f, 0.f, 0.f, 0.f};
            }
#pragma unroll
            for (int q = 0; q < 4; ++q)
#pragma unroll
                for (int g = 0; g < 4; ++g) {
                    a0[g] = __builtin_amdgcn_mfma_f32_16x16x32_f16(hh[q].v, Uh[g][q], a0[g], 0, 0, 0);
                    a1[g] = __builtin_amdgcn_mfma_f32_16x16x32_f16(hh[q].v, Ul[g][q], a1[g], 0, 0, 0);
                    a2[g] = __builtin_amdgcn_mfma_f32_16x16x32_f16(hl[q].v, Uh[g][q], a2[g], 0, 0, 0);
                }

            // single-buffer zpart, ONE barrier (dataflow implies write-order)
#pragma unroll
            for (int g = 0; g < 4; ++g)
#pragma unroll
                for (int r = 0; r < 4; ++r)
                    zpart[w][g][((lane >> 4) * 4 + r) * 16 + (lane & 15)] =
                        a0[g][r] + a1[g][r] + a2[g][r];
            __syncthreads();

            if (tid < 256) {
                const int zi_idx = b_own * 16 + jj_own;
                float zi = xw0, zf = xw1, zg = xw2, zo = xw3;
#pragma unroll
                for (int ww = 0; ww < 8; ++ww) {
                    zi += zpart[ww][0][zi_idx];
                    zf += zpart[ww][1][zi_idx];
                    zg += zpart[ww][2][zi_idx];
                    zo += zpart[ww][3][zi_idx];
                }
                float si = 1.f / (1.f + expf(-zi));
                float sf = 1.f / (1.f + expf(-zf));
                float so = 1.f / (1.f + expf(-zo));
                float c_new = sf * c_own + si * tanhf(zg);
                float h_new = so * tanhf(c_new);
                c_own = c_new;

                int hhi = (int)f16_bits(h_new);
                int hlo = (int)f16_bits(h_new - f16_f32((unsigned short)hhi));
                int hhi_nb = __shfl_xor(hhi, 1);
                int hlo_nb = __shfl_xor(hlo, 1);
                unsigned short* nh = hsl + (size_t)(t + 1) * 32768;
                if ((tid & 1) == 0) {   // jj even -> adjacent pair 4B-aligned
                    unsigned hp = (unsigned)(unsigned short)hhi | ((unsigned)(unsigned short)hhi_nb << 16);
                    unsigned lp = (unsigned)(unsigned short)hlo | ((unsigned)(unsigned short)hlo_nb << 16);
                    st_u32((unsigned*)(nh + hb_e), hp);
                    st_u32((unsigned*)(nh + 16384 + hb_e), lp);
                }
            }
            // no trailing barrier: next step's poll provides ordering.
        }
        return;
    }

    if (blockIdx.x < NB + EMB_BLKS) {
        // ================= embed/xW path: one t, 512 cols ==================
        const int eb  = blockIdx.x - NB;       // 0..1023
        const int t   = eb >> 3;               // ascending with dispatch order
        const int col = (eb & 7) * 512 + tid;
        float (*xs)[EMBED] = (float (*)[EMBED])smem_raw;   // [16][256], 16 KB
        int* toks = (int*)(smem_raw + 16384);
        if (tid < BATCH)
            toks[tid] = inputs[tid * SEQ + t];
        __syncthreads();
        for (int i = tid; i < BATCH * EMBED; i += 512)
            xs[i >> 8][i & 255] = emb[(size_t)toks[i >> 8] * EMBED + (i & 255)];
        __syncthreads();
        float acc[BATCH];
#pragma unroll
        for (int r = 0; r < BATCH; ++r) acc[r] = 0.f;
        for (int k0 = 0; k0 < EMBED; k0 += 4) {
            float4 xv[BATCH];
#pragma unroll
            for (int r = 0; r < BATCH; ++r)
                xv[r] = *(const float4*)(&xs[r][k0]);   // broadcast
#pragma unroll
            for (int e = 0; e < 4; ++e) {
                float wv = W[(size_t)(k0 + e) * GATES + col];
#pragma unroll
                for (int r = 0; r < BATCH; ++r)
                    acc[r] += ((const float*)&xv[r])[e] * wv;
            }
        }
        const float bb = bias[col];
        // sc1 stores -> visible at device coherence point (cross-XCD)
#pragma unroll
        for (int r = 0; r < BATCH; ++r)
            st_u32((unsigned*)&xWb[((size_t)t * BATCH + r) * GATES + col],
                   __builtin_bit_cast(unsigned, acc[r] + bb));
        asm volatile("s_waitcnt vmcnt(0)" ::: "memory");
        __syncthreads();
        if (tid == 0)
            st_u32(&xwf[t * 8 + (eb & 7)], 1u);
        return;
    }

    // ================= projection path (8-wave, mt2-major) =================
    unsigned short* Bs = (unsigned short*)smem_raw;   // fp16 bits, 16 KB
    const int bidp = blockIdx.x - NB - EMB_BLKS;      // 0..3999
    const int mt2 = bidp / 250;                       // t-group, ASCENDING
    const int nt  = bidp % 250;
    const int n0 = nt * 128;

    // ---- gate on slot (mt2*8+8) fully non-poison ----
    {
        const unsigned long long* gp =
            (const unsigned long long*)(hsl + (size_t)(mt2 * 8 + 8) * 32768);
        {
            const unsigned long long* sp = gp + (size_t)tid * 8;   // 512*8=4096
            unsigned long long v = ld_u64(sp);
            while (poison_u64(v)) {
                __builtin_amdgcn_s_sleep(32);
                v = ld_u64(sp);
            }
        }
        while (true) {
            unsigned bad = 0;
#pragma unroll
            for (int i = 0; i < 8; ++i)
                bad |= poison_u64(ld_u64(gp + (size_t)i * 512 + tid));
            if (__syncthreads_and((int)(bad == 0))) break;
            __builtin_amdgcn_s_sleep(16);
        }
        asm volatile("" ::: "memory");
    }

    // wave split: wmt = (w>>2)*4 t-rows, wn = (w&3)*32 n-cols
    const int b_kb  = (tid >> 5) * 8;     // staging coords (tid<256 only)
    const int b_nb4 = (tid & 31) * 4;
    const int wmt  = (w >> 2) * 4;
    const int wn   = (w & 3) * 32;
    const int lr   = lane & 15;
    const int kg   = lane >> 4;

    f32x4 acc[4][2];                      // [mi -> t][ni]
#pragma unroll
    for (int i = 0; i < 4; ++i)
#pragma unroll
        for (int j = 0; j < 2; ++j) acc[i][j] = (f32x4){0.f, 0.f, 0.f, 0.f};

    const unsigned short* aslot[4];
#pragma unroll
    for (int mi = 0; mi < 4; ++mi)
        aslot[mi] = hsl + (size_t)(mt2 * 8 + wmt + mi + 1) * 32768 + lane * 8;

    f16x8 A0h[4], A1h[4];
#pragma unroll
    for (int mi = 0; mi < 4; ++mi) {
        A0h[mi] = *(const f16x8*)(aslot[mi]);
        A1h[mi] = *(const f16x8*)(aslot[mi] + 512);
    }
    float4 rawB[8];
    if (tid < 256) {
#pragma unroll
        for (int i = 0; i < 8; ++i)
            rawB[i] = *(const float4*)(Wc + (size_t)(b_kb + i) * VOCAB + n0 + b_nb4);
    }

    for (int kt = 0; kt < 16; ++kt) {
        __syncthreads();
        if (tid < 256) {
#pragma unroll
            for (int nn = 0; nn < 4; ++nn) {
                unsigned short h8[8];
#pragma unroll
                for (int i = 0; i < 8; ++i)
                    h8[i] = f16_bits(((const float*)&rawB[i])[nn]);
                int e = swz_e(b_nb4 + nn, b_kb);
                *(s16x8*)(&Bs[e]) = *(const s16x8*)h8;
            }
        }
        __syncthreads();
        if (kt < 15 && tid < 256) {
            const int k0n = (kt + 1) * 64;
#pragma unroll
            for (int i = 0; i < 8; ++i)
                rawB[i] = *(const float4*)(Wc + (size_t)(k0n + b_kb + i) * VOCAB + n0 + b_nb4);
        }
        // ks = 0
        {
            f16x8 bh[2];
#pragma unroll
            for (int ni = 0; ni < 2; ++ni)
                bh[ni] = *(const f16x8*)(&Bs[swz_e(wn + ni * 16 + lr, kg * 8)]);
#pragma unroll
            for (int mi = 0; mi < 4; ++mi)
#pragma unroll
                for (int ni = 0; ni < 2; ++ni)
                    acc[mi][ni] = __builtin_amdgcn_mfma_f32_16x16x32_f16(A0h[mi], bh[ni], acc[mi][ni], 0, 0, 0);
            if (kt < 15) {
                const int base = (kt + 1) * 1024;
#pragma unroll
                for (int mi = 0; mi < 4; ++mi)
                    A0h[mi] = *(const f16x8*)(aslot[mi] + base);
            }
        }
        // ks = 1
        {
            f16x8 bh[2];
#pragma unroll
            for (int ni = 0; ni < 2; ++ni)
                bh[ni] = *(const f16x8*)(&Bs[swz_e(wn + ni * 16 + lr, 32 + kg * 8)]);
#pragma unroll
            for (int mi = 0; mi < 4; ++mi)
#pragma unroll
                for (int ni = 0; ni < 2; ++ni)
                    acc[mi][ni] = __builtin_amdgcn_mfma_f32_16x16x32_f16(A1h[mi], bh[ni], acc[mi][ni], 0, 0, 0);
            if (kt < 15) {
                const int base = (kt + 1) * 1024 + 512;
#pragma unroll
                for (int mi = 0; mi < 4; ++mi)
                    A1h[mi] = *(const f16x8*)(aslot[mi] + base);
            }
        }
    }

    // ---- epilogue: nontemporal stores (out never re-read; keep L3 for Wc/h)
    float bcv[2];
#pragma unroll
    for (int ni = 0; ni < 2; ++ni) bcv[ni] = bc[n0 + wn + ni * 16 + lr];
#pragma unroll
    for (int mi = 0; mi < 4; ++mi) {
        const int trow = mt2 * 8 + wmt + mi;
#pragma unroll
        for (int ni = 0; ni < 2; ++ni) {
#pragma unroll
            for (int r = 0; r < 4; ++r) {
                int grow = (kg * 4 + r) * 128 + trow;     // m = b*128 + t
                int gcol = n0 + wn + ni * 16 + lr;
                __builtin_nontemporal_store(acc[mi][ni][r] + bcv[ni],
                                            &out[(size_t)grow * VOCAB + gcol]);
            }
        }
    }
}

extern "C" void kernel_launch(void* const* d_in, const int* in_sizes, int n_in,
                              void* d_out, int out_size, void* d_ws, size_t ws_size,
                              hipStream_t stream) {
    const int*   inputs = (const int*)d_in[0];   // int32 (JAX x64 disabled)
    const float* emb  = (const float*)d_in[1];
    const float* W    = (const float*)d_in[2];
    const float* U    = (const float*)d_in[3];
    const float* bias = (const float*)d_in[4];
    const float* Wc   = (const float*)d_in[5];
    const float* bc   = (const float*)d_in[6];
    float* out = (float*)d_out;

    char* ws = (char*)d_ws;
    float*          xWb   = (float*)(ws + 0);
    unsigned short* ub_hi = (unsigned short*)(ws + 33554432);
    unsigned short* ub_lo = (unsigned short*)(ws + 41943040);
    unsigned short* hsl   = (unsigned short*)(ws + 50331648);
    unsigned*       xwf   = (unsigned*)(ws + 58785792);

    // slot 0 = h0 = 0; slots 1..128 poisoned 0xFFFF; xW flags = 0 — every call
    hipMemsetAsync(hsl, 0, 65536, stream);
    hipMemsetAsync((char*)hsl + 65536, 0xFF, 8454144 - 65536, stream);
    hipMemsetAsync(xwf, 0, 4096, stream);

    k_prep_u<<<256, 256, 0, stream>>>(U, ub_hi, ub_lo);
    k_fused<<<NB + EMB_BLKS + 4000, 512, 0, stream>>>(
        ub_hi, ub_lo, xWb, hsl, xwf, inputs, emb, W, bias, Wc, bc, out);
}

// Round 21
// 730.656 us; speedup vs baseline: 1.0133x; 1.0133x over previous
//
#include <hip/hip_runtime.h>
#include <hip/hip_bf16.h>
#include <math.h>

// LSTM language model. Round 21: r19 config (best stable: 733us; r17=731)
// with ONE isolated delta: recurrence poll s_sleep(8) -> s_sleep(2)
// (detection-latency on the 128-step serial chain, untested in isolation;
// r18 bundled it with two regressions).
// ws layout (~58.8 MB):
//   xWb    [128][16][4096] f32      33,554,432 B @ 0
//   ub_hi  [256ct][32kt][64][8] f16  8,388,608 B @ 33,554,432
//   ub_lo   (same)                   8,388,608 B @ 41,943,040
//   hslots [129][hi 16384 | lo 16384] ushort = 8,454,144 B @ 50,331,648
//          slot t: h_t fp16 hi/lo, elem(b,j) = (j>>5)*512 + (((j>>3)&3)*16+b)*8
//          + (j&7); slot 0 zeroed (h0), rest poisoned 0xFFFF (fp16 NaN).

#define VOCAB 32000
#define EMBED 256
#define UNITS 1024
#define GATES 4096
#define BATCH 16
#define SEQ 128
#define NB 64   // persistent recurrence blocks (16 cells each, 512 thr)

using s16x8 = __attribute__((ext_vector_type(8))) short;
using f16x8 = __attribute__((ext_vector_type(8))) _Float16;
using f32x4 = __attribute__((ext_vector_type(4))) float;

__device__ __forceinline__ unsigned short f16_bits(float x) {
    _Float16 h = (_Float16)x;                 // v_cvt_f16_f32, RNE
    return __builtin_bit_cast(unsigned short, h);
}
__device__ __forceinline__ float f16_f32(unsigned short b) {
    return (float)__builtin_bit_cast(_Float16, b);
}
__device__ __forceinline__ int swz_e(int r, int k) {
    return (r * 64 + k) ^ ((((r & 7) ^ ((r >> 2) & 7))) << 3);
}
__device__ __forceinline__ unsigned long long ld_u64(const unsigned long long* p) {
    return __hip_atomic_load(p, __ATOMIC_RELAXED, __HIP_MEMORY_SCOPE_AGENT);
}
__device__ __forceinline__ unsigned poison_u64(unsigned long long v) {
    return (unsigned)((unsigned)v == 0xFFFFFFFFu) |
           (unsigned)((unsigned)(v >> 32) == 0xFFFFFFFFu);
}

// ---------- K0: merged prep — blocks 0..255: U -> fp16 hi/lo fragments;
// blocks 256..2303: xWb = emb@W + bias (1 t per block) ----------
__global__ void __launch_bounds__(256) k_prep(
    const float* __restrict__ U,
    unsigned short* __restrict__ ub_hi,
    unsigned short* __restrict__ ub_lo,
    const int* __restrict__ inputs,
    const float* __restrict__ emb,
    const float* __restrict__ W,
    const float* __restrict__ bias,
    float* __restrict__ xWb) {
    __shared__ __align__(16) char smem_raw[65536];
    const int tid = threadIdx.x;

    if (blockIdx.x < 256) {
        // ---- U conversion (r13 layout) ----
        float* lds_u = (float*)smem_raw;       // [k][16 cols], 64 KB
        const int ct = blockIdx.x;
        for (int k = tid; k < 1024; k += 256) {
            const float4* src = (const float4*)(U + (size_t)k * GATES + ct * 16);
            float4* dst = (float4*)(&lds_u[k * 16]);
            dst[0] = src[0]; dst[1] = src[1]; dst[2] = src[2]; dst[3] = src[3];
        }
        __syncthreads();
        const int lane = tid & 63;
        const int coll = lane & 15;
        const int kg = lane >> 4;
        for (int kt = (tid >> 6); kt < 32; kt += 4) {
            const int ks = kt * 32 + kg * 8;
            unsigned short h8[8], l8[8];
#pragma unroll
            for (int e = 0; e < 8; ++e) {
                float v = lds_u[(ks + e) * 16 + coll];
                unsigned short hb = f16_bits(v);
                h8[e] = hb;
                l8[e] = f16_bits(v - f16_f32(hb));
            }
            size_t o = (((size_t)ct * 32 + kt) * 64 + lane) * 8;
            *(s16x8*)(ub_hi + o) = *(const s16x8*)h8;
            *(s16x8*)(ub_lo + o) = *(const s16x8*)l8;
        }
        return;
    }

    // ---- embed + xW (float4-broadcast xs reads) ----
    const int eb = blockIdx.x - 256;           // 0..2047
    const int t   = eb >> 4;                   // 0..127
    const int col = (eb & 15) * 256 + tid;     // 0..4095
    float (*xs)[EMBED] = (float (*)[EMBED])smem_raw;   // [16][256] f32, 16 KB
    int* toks = (int*)(smem_raw + 16384);
    if (tid < BATCH)
        toks[tid] = inputs[tid * SEQ + t];
    __syncthreads();
    for (int r = 0; r < BATCH; ++r)
        xs[r][tid] = emb[(size_t)toks[r] * EMBED + tid];
    __syncthreads();
    float acc[BATCH];
#pragma unroll
    for (int r = 0; r < BATCH; ++r) acc[r] = 0.f;
    for (int k0 = 0; k0 < EMBED; k0 += 4) {
        float4 xv[BATCH];
#pragma unroll
        for (int r = 0; r < BATCH; ++r)
            xv[r] = *(const float4*)(&xs[r][k0]);   // broadcast, conflict-free
#pragma unroll
        for (int e = 0; e < 4; ++e) {
            float w = W[(size_t)(k0 + e) * GATES + col];
#pragma unroll
            for (int r = 0; r < BATCH; ++r)
                acc[r] += ((const float*)&xv[r])[e] * w;
        }
    }
    const float bb = bias[col];
#pragma unroll
    for (int r = 0; r < BATCH; ++r)
        xWb[((size_t)t * BATCH + r) * GATES + col] = acc[r] + bb;
}

// ---------- K2: FUSED, 512 threads (8 waves) -------------------------------
// blocks 0..63: recurrence, 16 cells each; wave w covers k in [128w,128w+128)
// blocks 64..4063: projection 128x128, 8-wave split, mt2-major order.
__global__ void __launch_bounds__(512, 2) k_fused(
    const unsigned short* __restrict__ ub_hi,
    const unsigned short* __restrict__ ub_lo,
    const float* __restrict__ xWb,
    unsigned short* __restrict__ hsl,
    const float* __restrict__ Wc,
    const float* __restrict__ bc,
    float* __restrict__ out) {
    __shared__ __align__(16) char smem_raw[32768];
    const int tid  = threadIdx.x;
    const int lane = tid & 63;
    const int w    = tid >> 6;            // wave 0..7

    if (blockIdx.x < NB) {
        // ================= recurrence path =================
        __builtin_amdgcn_s_setprio(1);
        float (*zpart)[4][256] = (float (*)[4][256])smem_raw;  // [8][4][256] 32KB
        const int bid = blockIdx.x;
        const int j0  = bid * 16;

        const int b_own  = (tid >> 4) & 15;    // owners are tid<256
        const int jj_own = tid & 15;
        const int j_own  = j0 + jj_own;
        const int hb_e = ((j_own >> 5) * 512) + (((j_own >> 3) & 3) * 16 + b_own) * 8 + (j_own & 7);
        float c_own = 0.f;

        // preload U fragments (once): 4 gc-tiles x 4 kt per wave = 128 VGPR
        f16x8 Uh[4][4], Ul[4][4];
#pragma unroll
        for (int g = 0; g < 4; ++g)
#pragma unroll
            for (int q = 0; q < 4; ++q) {
                size_t o = (((size_t)(g * 64 + bid) * 32) + (w * 4 + q)) * 512 + lane * 8;
                Uh[g][q] = *(const f16x8*)(ub_hi + o);
                Ul[g][q] = *(const f16x8*)(ub_lo + o);
            }

        for (int t = 0; t < SEQ; ++t) {
            float xw0 = 0.f, xw1 = 0.f, xw2 = 0.f, xw3 = 0.f;
            if (tid < 256) {
                const float* xwp = xWb + ((size_t)t * BATCH + b_own) * GATES + j_own;
                xw0 = xwp[0]; xw1 = xwp[UNITS]; xw2 = xwp[2 * UNITS]; xw3 = xwp[3 * UNITS];
            }

            const unsigned long long* p64 =
                (const unsigned long long*)(hsl + (size_t)t * 32768);

            // ---- merged poll: the detecting load IS the data load ----
            union HU { unsigned long long q2[2]; f16x8 v; };
            HU hh[4], hl[4];
            while (true) {
                unsigned bad = 0;
#pragma unroll
                for (int q = 0; q < 4; ++q) {
                    const size_t u = (size_t)(w * 4 + q) * 128 + lane * 2;
                    hh[q].q2[0] = ld_u64(p64 + u);
                    hh[q].q2[1] = ld_u64(p64 + u + 1);
                    hl[q].q2[0] = ld_u64(p64 + 4096 + u);
                    hl[q].q2[1] = ld_u64(p64 + 4097 + u);
                }
#pragma unroll
                for (int q = 0; q < 4; ++q)
                    bad |= poison_u64(hh[q].q2[0]) | poison_u64(hh[q].q2[1]) |
                           poison_u64(hl[q].q2[0]) | poison_u64(hl[q].q2[1]);
                if (__all((int)(bad == 0))) break;
                __builtin_amdgcn_s_sleep(2);
            }

            f32x4 a0[4], a1[4], a2[4];
#pragma unroll
            for (int g = 0; g < 4; ++g) {
                a0[g] = (f32x4){0.f, 0.f, 0.f, 0.f};
                a1[g] = (f32x4){0.f, 0.f, 0.f, 0.f};
                a2[g] = (f32x4){0.f, 0.f, 0.f, 0.f};
            }
#pragma unroll
            for (int q = 0; q < 4; ++q)
#pragma unroll
                for (int g = 0; g < 4; ++g) {
                    a0[g] = __builtin_amdgcn_mfma_f32_16x16x32_f16(hh[q].v, Uh[g][q], a0[g], 0, 0, 0);
                    a1[g] = __builtin_amdgcn_mfma_f32_16x16x32_f16(hh[q].v, Ul[g][q], a1[g], 0, 0, 0);
                    a2[g] = __builtin_amdgcn_mfma_f32_16x16x32_f16(hl[q].v, Uh[g][q], a2[g], 0, 0, 0);
                }

            // single-buffer zpart, ONE barrier (dataflow implies write-order)
#pragma unroll
            for (int g = 0; g < 4; ++g)
#pragma unroll
                for (int r = 0; r < 4; ++r)
                    zpart[w][g][((lane >> 4) * 4 + r) * 16 + (lane & 15)] =
                        a0[g][r] + a1[g][r] + a2[g][r];
            __syncthreads();

            if (tid < 256) {
                const int zi_idx = b_own * 16 + jj_own;
                float zi = xw0, zf = xw1, zg = xw2, zo = xw3;
#pragma unroll
                for (int ww = 0; ww < 8; ++ww) {
                    zi += zpart[ww][0][zi_idx];
                    zf += zpart[ww][1][zi_idx];
                    zg += zpart[ww][2][zi_idx];
                    zo += zpart[ww][3][zi_idx];
                }
                float si = 1.f / (1.f + expf(-zi));
                float sf = 1.f / (1.f + expf(-zf));
                float so = 1.f / (1.f + expf(-zo));
                float c_new = sf * c_own + si * tanhf(zg);
                float h_new = so * tanhf(c_new);
                c_own = c_new;

                int hhi = (int)f16_bits(h_new);
                int hlo = (int)f16_bits(h_new - f16_f32((unsigned short)hhi));
                int hhi_nb = __shfl_xor(hhi, 1);
                int hlo_nb = __shfl_xor(hlo, 1);
                unsigned short* nh = hsl + (size_t)(t + 1) * 32768;
                if ((tid & 1) == 0) {   // jj even -> adjacent pair 4B-aligned
                    unsigned hp = (unsigned)(unsigned short)hhi | ((unsigned)(unsigned short)hhi_nb << 16);
                    unsigned lp = (unsigned)(unsigned short)hlo | ((unsigned)(unsigned short)hlo_nb << 16);
                    __hip_atomic_store((unsigned*)(nh + hb_e), hp,
                                       __ATOMIC_RELAXED, __HIP_MEMORY_SCOPE_AGENT);
                    __hip_atomic_store((unsigned*)(nh + 16384 + hb_e), lp,
                                       __ATOMIC_RELAXED, __HIP_MEMORY_SCOPE_AGENT);
                }
            }
            // no trailing barrier: next step's poll provides ordering.
        }
        return;
    }

    // ================= projection path (8-wave, mt2-major) =================
    // A = h hi ONLY (fp16 RNE of h): error budget allows dropping the lo pass.
    unsigned short* Bs = (unsigned short*)smem_raw;   // fp16 bits, 16 KB
    const int bidp = blockIdx.x - NB;                 // 0..3999
    const int mt2 = bidp / 250;                       // t-group, ASCENDING
    const int nt  = bidp % 250;
    const int n0 = nt * 128;

    // ---- gate on slot (mt2*8+8) fully non-poison ----
    {
        const unsigned long long* gp =
            (const unsigned long long*)(hsl + (size_t)(mt2 * 8 + 8) * 32768);
        {
            const unsigned long long* sp = gp + (size_t)tid * 8;   // 512*8=4096
            unsigned long long v = ld_u64(sp);
            while (poison_u64(v)) {
                __builtin_amdgcn_s_sleep(32);
                v = ld_u64(sp);
            }
        }
        while (true) {
            unsigned bad = 0;
#pragma unroll
            for (int i = 0; i < 8; ++i)
                bad |= poison_u64(ld_u64(gp + (size_t)i * 512 + tid));
            if (__syncthreads_and((int)(bad == 0))) break;
            __builtin_amdgcn_s_sleep(16);
        }
        asm volatile("" ::: "memory");
    }

    // wave split: wmt = (w>>2)*4 t-rows, wn = (w&3)*32 n-cols
    const int b_kb  = (tid >> 5) * 8;     // staging coords (tid<256 only)
    const int b_nb4 = (tid & 31) * 4;
    const int wmt  = (w >> 2) * 4;
    const int wn   = (w & 3) * 32;
    const int lr   = lane & 15;
    const int kg   = lane >> 4;

    f32x4 acc[4][2];                      // [mi -> t][ni]
#pragma unroll
    for (int i = 0; i < 4; ++i)
#pragma unroll
        for (int j = 0; j < 2; ++j) acc[i][j] = (f32x4){0.f, 0.f, 0.f, 0.f};

    const unsigned short* aslot[4];
#pragma unroll
    for (int mi = 0; mi < 4; ++mi)
        aslot[mi] = hsl + (size_t)(mt2 * 8 + wmt + mi + 1) * 32768 + lane * 8;

    f16x8 A0h[4], A1h[4];
#pragma unroll
    for (int mi = 0; mi < 4; ++mi) {
        A0h[mi] = *(const f16x8*)(aslot[mi]);
        A1h[mi] = *(const f16x8*)(aslot[mi] + 512);
    }
    float4 rawB[8];
    if (tid < 256) {
#pragma unroll
        for (int i = 0; i < 8; ++i)
            rawB[i] = *(const float4*)(Wc + (size_t)(b_kb + i) * VOCAB + n0 + b_nb4);
    }

    for (int kt = 0; kt < 16; ++kt) {
        __syncthreads();
        if (tid < 256) {
#pragma unroll
            for (int nn = 0; nn < 4; ++nn) {
                unsigned short h8[8];
#pragma unroll
                for (int i = 0; i < 8; ++i)
                    h8[i] = f16_bits(((const float*)&rawB[i])[nn]);
                int e = swz_e(b_nb4 + nn, b_kb);
                *(s16x8*)(&Bs[e]) = *(const s16x8*)h8;
            }
        }
        __syncthreads();
        if (kt < 15 && tid < 256) {
            const int k0n = (kt + 1) * 64;
#pragma unroll
            for (int i = 0; i < 8; ++i)
                rawB[i] = *(const float4*)(Wc + (size_t)(k0n + b_kb + i) * VOCAB + n0 + b_nb4);
        }
        // ks = 0
        {
            f16x8 bh[2];
#pragma unroll
            for (int ni = 0; ni < 2; ++ni)
                bh[ni] = *(const f16x8*)(&Bs[swz_e(wn + ni * 16 + lr, kg * 8)]);
#pragma unroll
            for (int mi = 0; mi < 4; ++mi)
#pragma unroll
                for (int ni = 0; ni < 2; ++ni)
                    acc[mi][ni] = __builtin_amdgcn_mfma_f32_16x16x32_f16(A0h[mi], bh[ni], acc[mi][ni], 0, 0, 0);
            if (kt < 15) {
                const int base = (kt + 1) * 1024;
#pragma unroll
                for (int mi = 0; mi < 4; ++mi)
                    A0h[mi] = *(const f16x8*)(aslot[mi] + base);
            }
        }
        // ks = 1
        {
            f16x8 bh[2];
#pragma unroll
            for (int ni = 0; ni < 2; ++ni)
                bh[ni] = *(const f16x8*)(&Bs[swz_e(wn + ni * 16 + lr, 32 + kg * 8)]);
#pragma unroll
            for (int mi = 0; mi < 4; ++mi)
#pragma unroll
                for (int ni = 0; ni < 2; ++ni)
                    acc[mi][ni] = __builtin_amdgcn_mfma_f32_16x16x32_f16(A1h[mi], bh[ni], acc[mi][ni], 0, 0, 0);
            if (kt < 15) {
                const int base = (kt + 1) * 1024 + 512;
#pragma unroll
                for (int mi = 0; mi < 4; ++mi)
                    A1h[mi] = *(const f16x8*)(aslot[mi] + base);
            }
        }
    }

    // ---- epilogue: nontemporal stores (out never re-read; keep L3 for Wc/h)
    float bcv[2];
#pragma unroll
    for (int ni = 0; ni < 2; ++ni) bcv[ni] = bc[n0 + wn + ni * 16 + lr];
#pragma unroll
    for (int mi = 0; mi < 4; ++mi) {
        const int trow = mt2 * 8 + wmt + mi;
#pragma unroll
        for (int ni = 0; ni < 2; ++ni) {
#pragma unroll
            for (int r = 0; r < 4; ++r) {
                int grow = (kg * 4 + r) * 128 + trow;     // m = b*128 + t
                int gcol = n0 + wn + ni * 16 + lr;
                __builtin_nontemporal_store(acc[mi][ni][r] + bcv[ni],
                                            &out[(size_t)grow * VOCAB + gcol]);
            }
        }
    }
}

extern "C" void kernel_launch(void* const* d_in, const int* in_sizes, int n_in,
                              void* d_out, int out_size, void* d_ws, size_t ws_size,
                              hipStream_t stream) {
    const int*   inputs = (const int*)d_in[0];   // int32 (JAX x64 disabled)
    const float* emb  = (const float*)d_in[1];
    const float* W    = (const float*)d_in[2];
    const float* U    = (const float*)d_in[3];
    const float* bias = (const float*)d_in[4];
    const float* Wc   = (const float*)d_in[5];
    const float* bc   = (const float*)d_in[6];
    float* out = (float*)d_out;

    char* ws = (char*)d_ws;
    float*          xWb   = (float*)(ws + 0);
    unsigned short* ub_hi = (unsigned short*)(ws + 33554432);
    unsigned short* ub_lo = (unsigned short*)(ws + 41943040);
    unsigned short* hsl   = (unsigned short*)(ws + 50331648);

    // slot 0 = h0 = 0 (valid); slots 1..128 poisoned 0xFFFF — every call
    hipMemsetAsync(hsl, 0, 65536, stream);
    hipMemsetAsync((char*)hsl + 65536, 0xFF, 8454144 - 65536, stream);

    k_prep<<<256 + 2048, 256, 0, stream>>>(U, ub_hi, ub_lo,
                                           inputs, emb, W, bias, xWb);
    k_fused<<<NB + 4000, 512, 0, stream>>>(ub_hi, ub_lo, xWb, hsl, Wc, bc, out);
}

// Round 22
// 679.038 us; speedup vs baseline: 1.0903x; 1.0760x over previous
//
#include <hip/hip_runtime.h>
#include <hip/hip_bf16.h>
#include <math.h>

// LSTM language model. Round 22: r21 config with ONE isolated delta — the
// recurrence drops the h-LO plane entirely (h broadcast = fp16 hi only):
// poll volume halves, MFMA chains 3->2, h stores halve. U stays hi/lo,
// xW stays f32, projection (already hi-only) untouched.
// Error budget: +~2.8e-4 logit absmax (fp16 h quantization, contractive),
// total predicted 2.5-4.5e-4 vs threshold 7.96e-4.
// ws layout (~58.8 MB):
//   xWb    [128][16][4096] f32      33,554,432 B @ 0
//   ub_hi  [256ct][32kt][64][8] f16  8,388,608 B @ 33,554,432
//   ub_lo   (same)                   8,388,608 B @ 41,943,040
//   hslots [129][hi 16384 | lo 16384] ushort = 8,454,144 B @ 50,331,648
//          (lo plane now unused); slot 0 zeroed (h0), rest poisoned 0xFFFF.

#define VOCAB 32000
#define EMBED 256
#define UNITS 1024
#define GATES 4096
#define BATCH 16
#define SEQ 128
#define NB 64   // persistent recurrence blocks (16 cells each, 512 thr)

using s16x8 = __attribute__((ext_vector_type(8))) short;
using f16x8 = __attribute__((ext_vector_type(8))) _Float16;
using f32x4 = __attribute__((ext_vector_type(4))) float;

__device__ __forceinline__ unsigned short f16_bits(float x) {
    _Float16 h = (_Float16)x;                 // v_cvt_f16_f32, RNE
    return __builtin_bit_cast(unsigned short, h);
}
__device__ __forceinline__ float f16_f32(unsigned short b) {
    return (float)__builtin_bit_cast(_Float16, b);
}
__device__ __forceinline__ int swz_e(int r, int k) {
    return (r * 64 + k) ^ ((((r & 7) ^ ((r >> 2) & 7))) << 3);
}
__device__ __forceinline__ unsigned long long ld_u64(const unsigned long long* p) {
    return __hip_atomic_load(p, __ATOMIC_RELAXED, __HIP_MEMORY_SCOPE_AGENT);
}
__device__ __forceinline__ unsigned poison_u64(unsigned long long v) {
    return (unsigned)((unsigned)v == 0xFFFFFFFFu) |
           (unsigned)((unsigned)(v >> 32) == 0xFFFFFFFFu);
}

// ---------- K0: merged prep — blocks 0..255: U -> fp16 hi/lo fragments;
// blocks 256..2303: xWb = emb@W + bias (1 t per block) ----------
__global__ void __launch_bounds__(256) k_prep(
    const float* __restrict__ U,
    unsigned short* __restrict__ ub_hi,
    unsigned short* __restrict__ ub_lo,
    const int* __restrict__ inputs,
    const float* __restrict__ emb,
    const float* __restrict__ W,
    const float* __restrict__ bias,
    float* __restrict__ xWb) {
    __shared__ __align__(16) char smem_raw[65536];
    const int tid = threadIdx.x;

    if (blockIdx.x < 256) {
        // ---- U conversion (r13 layout) ----
        float* lds_u = (float*)smem_raw;       // [k][16 cols], 64 KB
        const int ct = blockIdx.x;
        for (int k = tid; k < 1024; k += 256) {
            const float4* src = (const float4*)(U + (size_t)k * GATES + ct * 16);
            float4* dst = (float4*)(&lds_u[k * 16]);
            dst[0] = src[0]; dst[1] = src[1]; dst[2] = src[2]; dst[3] = src[3];
        }
        __syncthreads();
        const int lane = tid & 63;
        const int coll = lane & 15;
        const int kg = lane >> 4;
        for (int kt = (tid >> 6); kt < 32; kt += 4) {
            const int ks = kt * 32 + kg * 8;
            unsigned short h8[8], l8[8];
#pragma unroll
            for (int e = 0; e < 8; ++e) {
                float v = lds_u[(ks + e) * 16 + coll];
                unsigned short hb = f16_bits(v);
                h8[e] = hb;
                l8[e] = f16_bits(v - f16_f32(hb));
            }
            size_t o = (((size_t)ct * 32 + kt) * 64 + lane) * 8;
            *(s16x8*)(ub_hi + o) = *(const s16x8*)h8;
            *(s16x8*)(ub_lo + o) = *(const s16x8*)l8;
        }
        return;
    }

    // ---- embed + xW (float4-broadcast xs reads) ----
    const int eb = blockIdx.x - 256;           // 0..2047
    const int t   = eb >> 4;                   // 0..127
    const int col = (eb & 15) * 256 + tid;     // 0..4095
    float (*xs)[EMBED] = (float (*)[EMBED])smem_raw;   // [16][256] f32, 16 KB
    int* toks = (int*)(smem_raw + 16384);
    if (tid < BATCH)
        toks[tid] = inputs[tid * SEQ + t];
    __syncthreads();
    for (int r = 0; r < BATCH; ++r)
        xs[r][tid] = emb[(size_t)toks[r] * EMBED + tid];
    __syncthreads();
    float acc[BATCH];
#pragma unroll
    for (int r = 0; r < BATCH; ++r) acc[r] = 0.f;
    for (int k0 = 0; k0 < EMBED; k0 += 4) {
        float4 xv[BATCH];
#pragma unroll
        for (int r = 0; r < BATCH; ++r)
            xv[r] = *(const float4*)(&xs[r][k0]);   // broadcast, conflict-free
#pragma unroll
        for (int e = 0; e < 4; ++e) {
            float w = W[(size_t)(k0 + e) * GATES + col];
#pragma unroll
            for (int r = 0; r < BATCH; ++r)
                acc[r] += ((const float*)&xv[r])[e] * w;
        }
    }
    const float bb = bias[col];
#pragma unroll
    for (int r = 0; r < BATCH; ++r)
        xWb[((size_t)t * BATCH + r) * GATES + col] = acc[r] + bb;
}

// ---------- K2: FUSED, 512 threads (8 waves) -------------------------------
// blocks 0..63: recurrence, 16 cells each; wave w covers k in [128w,128w+128)
// blocks 64..4063: projection 128x128, 8-wave split, mt2-major order.
__global__ void __launch_bounds__(512, 2) k_fused(
    const unsigned short* __restrict__ ub_hi,
    const unsigned short* __restrict__ ub_lo,
    const float* __restrict__ xWb,
    unsigned short* __restrict__ hsl,
    const float* __restrict__ Wc,
    const float* __restrict__ bc,
    float* __restrict__ out) {
    __shared__ __align__(16) char smem_raw[32768];
    const int tid  = threadIdx.x;
    const int lane = tid & 63;
    const int w    = tid >> 6;            // wave 0..7

    if (blockIdx.x < NB) {
        // ================= recurrence path (h = fp16 hi ONLY) ==============
        __builtin_amdgcn_s_setprio(1);
        float (*zpart)[4][256] = (float (*)[4][256])smem_raw;  // [8][4][256] 32KB
        const int bid = blockIdx.x;
        const int j0  = bid * 16;

        const int b_own  = (tid >> 4) & 15;    // owners are tid<256
        const int jj_own = tid & 15;
        const int j_own  = j0 + jj_own;
        const int hb_e = ((j_own >> 5) * 512) + (((j_own >> 3) & 3) * 16 + b_own) * 8 + (j_own & 7);
        float c_own = 0.f;

        // preload U fragments (once): 4 gc-tiles x 4 kt per wave = 128 VGPR
        f16x8 Uh[4][4], Ul[4][4];
#pragma unroll
        for (int g = 0; g < 4; ++g)
#pragma unroll
            for (int q = 0; q < 4; ++q) {
                size_t o = (((size_t)(g * 64 + bid) * 32) + (w * 4 + q)) * 512 + lane * 8;
                Uh[g][q] = *(const f16x8*)(ub_hi + o);
                Ul[g][q] = *(const f16x8*)(ub_lo + o);
            }

        for (int t = 0; t < SEQ; ++t) {
            float xw0 = 0.f, xw1 = 0.f, xw2 = 0.f, xw3 = 0.f;
            if (tid < 256) {
                const float* xwp = xWb + ((size_t)t * BATCH + b_own) * GATES + j_own;
                xw0 = xwp[0]; xw1 = xwp[UNITS]; xw2 = xwp[2 * UNITS]; xw3 = xwp[3 * UNITS];
            }

            const unsigned long long* p64 =
                (const unsigned long long*)(hsl + (size_t)t * 32768);

            // ---- merged poll (hi plane only): detecting load IS data load --
            union HU { unsigned long long q2[2]; f16x8 v; };
            HU hh[4];
            while (true) {
                unsigned bad = 0;
#pragma unroll
                for (int q = 0; q < 4; ++q) {
                    const size_t u = (size_t)(w * 4 + q) * 128 + lane * 2;
                    hh[q].q2[0] = ld_u64(p64 + u);
                    hh[q].q2[1] = ld_u64(p64 + u + 1);
                }
#pragma unroll
                for (int q = 0; q < 4; ++q)
                    bad |= poison_u64(hh[q].q2[0]) | poison_u64(hh[q].q2[1]);
                if (__all((int)(bad == 0))) break;
                __builtin_amdgcn_s_sleep(2);
            }

            f32x4 a0[4], a1[4];
#pragma unroll
            for (int g = 0; g < 4; ++g) {
                a0[g] = (f32x4){0.f, 0.f, 0.f, 0.f};
                a1[g] = (f32x4){0.f, 0.f, 0.f, 0.f};
            }
#pragma unroll
            for (int q = 0; q < 4; ++q)
#pragma unroll
                for (int g = 0; g < 4; ++g) {
                    a0[g] = __builtin_amdgcn_mfma_f32_16x16x32_f16(hh[q].v, Uh[g][q], a0[g], 0, 0, 0);
                    a1[g] = __builtin_amdgcn_mfma_f32_16x16x32_f16(hh[q].v, Ul[g][q], a1[g], 0, 0, 0);
                }

            // single-buffer zpart, ONE barrier (dataflow implies write-order)
#pragma unroll
            for (int g = 0; g < 4; ++g)
#pragma unroll
                for (int r = 0; r < 4; ++r)
                    zpart[w][g][((lane >> 4) * 4 + r) * 16 + (lane & 15)] =
                        a0[g][r] + a1[g][r];
            __syncthreads();

            if (tid < 256) {
                const int zi_idx = b_own * 16 + jj_own;
                float zi = xw0, zf = xw1, zg = xw2, zo = xw3;
#pragma unroll
                for (int ww = 0; ww < 8; ++ww) {
                    zi += zpart[ww][0][zi_idx];
                    zf += zpart[ww][1][zi_idx];
                    zg += zpart[ww][2][zi_idx];
                    zo += zpart[ww][3][zi_idx];
                }
                float si = 1.f / (1.f + expf(-zi));
                float sf = 1.f / (1.f + expf(-zf));
                float so = 1.f / (1.f + expf(-zo));
                float c_new = sf * c_own + si * tanhf(zg);
                float h_new = so * tanhf(c_new);
                c_own = c_new;

                int hhi = (int)f16_bits(h_new);
                int hhi_nb = __shfl_xor(hhi, 1);
                unsigned short* nh = hsl + (size_t)(t + 1) * 32768;
                if ((tid & 1) == 0) {   // jj even -> adjacent pair 4B-aligned
                    unsigned hp = (unsigned)(unsigned short)hhi | ((unsigned)(unsigned short)hhi_nb << 16);
                    __hip_atomic_store((unsigned*)(nh + hb_e), hp,
                                       __ATOMIC_RELAXED, __HIP_MEMORY_SCOPE_AGENT);
                }
            }
            // no trailing barrier: next step's poll provides ordering.
        }
        return;
    }

    // ================= projection path (8-wave, mt2-major) =================
    // A = h hi ONLY (fp16 RNE of h).
    unsigned short* Bs = (unsigned short*)smem_raw;   // fp16 bits, 16 KB
    const int bidp = blockIdx.x - NB;                 // 0..3999
    const int mt2 = bidp / 250;                       // t-group, ASCENDING
    const int nt  = bidp % 250;
    const int n0 = nt * 128;

    // ---- gate on slot (mt2*8+8) hi plane fully non-poison ----
    {
        const unsigned long long* gp =
            (const unsigned long long*)(hsl + (size_t)(mt2 * 8 + 8) * 32768);
        {
            const unsigned long long* sp = gp + (size_t)tid * 8;   // 512*8=4096
            unsigned long long v = ld_u64(sp);
            while (poison_u64(v)) {
                __builtin_amdgcn_s_sleep(32);
                v = ld_u64(sp);
            }
        }
        while (true) {
            unsigned bad = 0;
#pragma unroll
            for (int i = 0; i < 8; ++i)
                bad |= poison_u64(ld_u64(gp + (size_t)i * 512 + tid));
            if (__syncthreads_and((int)(bad == 0))) break;
            __builtin_amdgcn_s_sleep(16);
        }
        asm volatile("" ::: "memory");
    }

    // wave split: wmt = (w>>2)*4 t-rows, wn = (w&3)*32 n-cols
    const int b_kb  = (tid >> 5) * 8;     // staging coords (tid<256 only)
    const int b_nb4 = (tid & 31) * 4;
    const int wmt  = (w >> 2) * 4;
    const int wn   = (w & 3) * 32;
    const int lr   = lane & 15;
    const int kg   = lane >> 4;

    f32x4 acc[4][2];                      // [mi -> t][ni]
#pragma unroll
    for (int i = 0; i < 4; ++i)
#pragma unroll
        for (int j = 0; j < 2; ++j) acc[i][j] = (f32x4){0.f, 0.f, 0.f, 0.f};

    const unsigned short* aslot[4];
#pragma unroll
    for (int mi = 0; mi < 4; ++mi)
        aslot[mi] = hsl + (size_t)(mt2 * 8 + wmt + mi + 1) * 32768 + lane * 8;

    f16x8 A0h[4], A1h[4];
#pragma unroll
    for (int mi = 0; mi < 4; ++mi) {
        A0h[mi] = *(const f16x8*)(aslot[mi]);
        A1h[mi] = *(const f16x8*)(aslot[mi] + 512);
    }
    float4 rawB[8];
    if (tid < 256) {
#pragma unroll
        for (int i = 0; i < 8; ++i)
            rawB[i] = *(const float4*)(Wc + (size_t)(b_kb + i) * VOCAB + n0 + b_nb4);
    }

    for (int kt = 0; kt < 16; ++kt) {
        __syncthreads();
        if (tid < 256) {
#pragma unroll
            for (int nn = 0; nn < 4; ++nn) {
                unsigned short h8[8];
#pragma unroll
                for (int i = 0; i < 8; ++i)
                    h8[i] = f16_bits(((const float*)&rawB[i])[nn]);
                int e = swz_e(b_nb4 + nn, b_kb);
                *(s16x8*)(&Bs[e]) = *(const s16x8*)h8;
            }
        }
        __syncthreads();
        if (kt < 15 && tid < 256) {
            const int k0n = (kt + 1) * 64;
#pragma unroll
            for (int i = 0; i < 8; ++i)
                rawB[i] = *(const float4*)(Wc + (size_t)(k0n + b_kb + i) * VOCAB + n0 + b_nb4);
        }
        // ks = 0
        {
            f16x8 bh[2];
#pragma unroll
            for (int ni = 0; ni < 2; ++ni)
                bh[ni] = *(const f16x8*)(&Bs[swz_e(wn + ni * 16 + lr, kg * 8)]);
#pragma unroll
            for (int mi = 0; mi < 4; ++mi)
#pragma unroll
                for (int ni = 0; ni < 2; ++ni)
                    acc[mi][ni] = __builtin_amdgcn_mfma_f32_16x16x32_f16(A0h[mi], bh[ni], acc[mi][ni], 0, 0, 0);
            if (kt < 15) {
                const int base = (kt + 1) * 1024;
#pragma unroll
                for (int mi = 0; mi < 4; ++mi)
                    A0h[mi] = *(const f16x8*)(aslot[mi] + base);
            }
        }
        // ks = 1
        {
            f16x8 bh[2];
#pragma unroll
            for (int ni = 0; ni < 2; ++ni)
                bh[ni] = *(const f16x8*)(&Bs[swz_e(wn + ni * 16 + lr, 32 + kg * 8)]);
#pragma unroll
            for (int mi = 0; mi < 4; ++mi)
#pragma unroll
                for (int ni = 0; ni < 2; ++ni)
                    acc[mi][ni] = __builtin_amdgcn_mfma_f32_16x16x32_f16(A1h[mi], bh[ni], acc[mi][ni], 0, 0, 0);
            if (kt < 15) {
                const int base = (kt + 1) * 1024 + 512;
#pragma unroll
                for (int mi = 0; mi < 4; ++mi)
                    A1h[mi] = *(const f16x8*)(aslot[mi] + base);
            }
        }
    }

    // ---- epilogue: nontemporal stores (out never re-read; keep L3 for Wc/h)
    float bcv[2];
#pragma unroll
    for (int ni = 0; ni < 2; ++ni) bcv[ni] = bc[n0 + wn + ni * 16 + lr];
#pragma unroll
    for (int mi = 0; mi < 4; ++mi) {
        const int trow = mt2 * 8 + wmt + mi;
#pragma unroll
        for (int ni = 0; ni < 2; ++ni) {
#pragma unroll
            for (int r = 0; r < 4; ++r) {
                int grow = (kg * 4 + r) * 128 + trow;     // m = b*128 + t
                int gcol = n0 + wn + ni * 16 + lr;
                __builtin_nontemporal_store(acc[mi][ni][r] + bcv[ni],
                                            &out[(size_t)grow * VOCAB + gcol]);
            }
        }
    }
}

extern "C" void kernel_launch(void* const* d_in, const int* in_sizes, int n_in,
                              void* d_out, int out_size, void* d_ws, size_t ws_size,
                              hipStream_t stream) {
    const int*   inputs = (const int*)d_in[0];   // int32 (JAX x64 disabled)
    const float* emb  = (const float*)d_in[1];
    const float* W    = (const float*)d_in[2];
    const float* U    = (const float*)d_in[3];
    const float* bias = (const float*)d_in[4];
    const float* Wc   = (const float*)d_in[5];
    const float* bc   = (const float*)d_in[6];
    float* out = (float*)d_out;

    char* ws = (char*)d_ws;
    float*          xWb   = (float*)(ws + 0);
    unsigned short* ub_hi = (unsigned short*)(ws + 33554432);
    unsigned short* ub_lo = (unsigned short*)(ws + 41943040);
    unsigned short* hsl   = (unsigned short*)(ws + 50331648);

    // slot 0 = h0 = 0 (valid); slots 1..128 poisoned 0xFFFF — every call
    hipMemsetAsync(hsl, 0, 65536, stream);
    hipMemsetAsync((char*)hsl + 65536, 0xFF, 8454144 - 65536, stream);

    k_prep<<<256 + 2048, 256, 0, stream>>>(U, ub_hi, ub_lo,
                                           inputs, emb, W, bias, xWb);
    k_fused<<<NB + 4000, 512, 0, stream>>>(ub_hi, ub_lo, xWb, hsl, Wc, bc, out);
}

// Round 23
// 592.910 us; speedup vs baseline: 1.2487x; 1.1453x over previous
//
#include <hip/hip_runtime.h>
#include <hip/hip_bf16.h>
#include <math.h>

// LSTM language model. Round 23: embed/xW prep rewritten as fp16 MFMA GEMM
// (r3-proven 128x128 tile pattern; K=256, 512 blocks) — was 4.3 GF of
// scalar fp32 VALU (~75us). k_fused byte-identical to round 22 (679us best).
// ws layout (~58.8 MB):
//   xWb    [128][16][4096] f32      33,554,432 B @ 0
//   ub_hi  [256ct][32kt][64][8] f16  8,388,608 B @ 33,554,432
//   ub_lo   (same)                   8,388,608 B @ 41,943,040
//   hslots [129][hi 16384 | lo 16384] ushort = 8,454,144 B @ 50,331,648
//          (lo plane unused); slot 0 zeroed (h0), rest poisoned 0xFFFF.

#define VOCAB 32000
#define EMBED 256
#define UNITS 1024
#define GATES 4096
#define BATCH 16
#define SEQ 128
#define NB 64   // persistent recurrence blocks (16 cells each, 512 thr)

using s16x8 = __attribute__((ext_vector_type(8))) short;
using f16x8 = __attribute__((ext_vector_type(8))) _Float16;
using f32x4 = __attribute__((ext_vector_type(4))) float;

__device__ __forceinline__ unsigned short f16_bits(float x) {
    _Float16 h = (_Float16)x;                 // v_cvt_f16_f32, RNE
    return __builtin_bit_cast(unsigned short, h);
}
__device__ __forceinline__ float f16_f32(unsigned short b) {
    return (float)__builtin_bit_cast(_Float16, b);
}
__device__ __forceinline__ int swz_e(int r, int k) {
    return (r * 64 + k) ^ ((((r & 7) ^ ((r >> 2) & 7))) << 3);
}
__device__ __forceinline__ unsigned long long ld_u64(const unsigned long long* p) {
    return __hip_atomic_load(p, __ATOMIC_RELAXED, __HIP_MEMORY_SCOPE_AGENT);
}
__device__ __forceinline__ unsigned poison_u64(unsigned long long v) {
    return (unsigned)((unsigned)v == 0xFFFFFFFFu) |
           (unsigned)((unsigned)(v >> 32) == 0xFFFFFFFFu);
}

// ---------- K0: merged prep — blocks 0..255: U -> fp16 hi/lo fragments;
// blocks 256..767: xWb = emb@W + bias via fp16 MFMA GEMM (r3 tile) ----------
__global__ void __launch_bounds__(256) k_prep(
    const float* __restrict__ U,
    unsigned short* __restrict__ ub_hi,
    unsigned short* __restrict__ ub_lo,
    const int* __restrict__ inputs,
    const float* __restrict__ emb,
    const float* __restrict__ W,
    const float* __restrict__ bias,
    float* __restrict__ xWb) {
    __shared__ __align__(16) char smem_raw[65536];
    const int tid = threadIdx.x;

    if (blockIdx.x < 256) {
        // ---- U conversion (r13 layout) ----
        float* lds_u = (float*)smem_raw;       // [k][16 cols], 64 KB
        const int ct = blockIdx.x;
        for (int k = tid; k < 1024; k += 256) {
            const float4* src = (const float4*)(U + (size_t)k * GATES + ct * 16);
            float4* dst = (float4*)(&lds_u[k * 16]);
            dst[0] = src[0]; dst[1] = src[1]; dst[2] = src[2]; dst[3] = src[3];
        }
        __syncthreads();
        const int lane = tid & 63;
        const int coll = lane & 15;
        const int kg = lane >> 4;
        for (int kt = (tid >> 6); kt < 32; kt += 4) {
            const int ks = kt * 32 + kg * 8;
            unsigned short h8[8], l8[8];
#pragma unroll
            for (int e = 0; e < 8; ++e) {
                float v = lds_u[(ks + e) * 16 + coll];
                unsigned short hb = f16_bits(v);
                h8[e] = hb;
                l8[e] = f16_bits(v - f16_f32(hb));
            }
            size_t o = (((size_t)ct * 32 + kt) * 64 + lane) * 8;
            *(s16x8*)(ub_hi + o) = *(const s16x8*)h8;
            *(s16x8*)(ub_lo + o) = *(const s16x8*)l8;
        }
        return;
    }

    // ---- xW GEMM: m = t*16+b (2048 rows), n = 4096 cols, K = 256 ----
    // 512 blocks: mt = bid2 & 15 (128 rows = 8 t x 16 b), nt = bid2 >> 4.
    unsigned short* As = (unsigned short*)smem_raw;            // [128][64] swz
    unsigned short* Bs = (unsigned short*)(smem_raw + 16384);  // [128][64] swz
    int* toks = (int*)(smem_raw + 32768);                      // [128]
    const int bid2 = blockIdx.x - 256;
    const int mt = bid2 & 15;
    const int nt = bid2 >> 4;
    const int n0 = nt * 128;

    const int lane = tid & 63;
    const int w4   = tid >> 6;
    const int wm   = (w4 >> 1) * 64;
    const int wn   = (w4 & 1) * 64;
    const int lr   = lane & 15;
    const int kg   = lane >> 4;

    if (tid < 128) {
        const int m = mt * 128 + tid;
        toks[tid] = inputs[(m & 15) * SEQ + (m >> 4)];   // b*SEQ + t
    }

    f32x4 acc[4][4];
#pragma unroll
    for (int i = 0; i < 4; ++i)
#pragma unroll
        for (int j = 0; j < 4; ++j) acc[i][j] = (f32x4){0.f, 0.f, 0.f, 0.f};

    const int a_r = tid >> 1;              // A row 0..127
    const int a_c = (tid & 1) * 32;        // k-offset within 64
    const int b_kb  = (tid >> 5) * 8;
    const int b_nb4 = (tid & 31) * 4;

    for (int kt = 0; kt < 4; ++kt) {
        __syncthreads();   // prior frag reads done; kt=0: toks visible
        // ---- stage A: emb rows -> fp16, swizzled (32 f32/thread) ----
        {
            const float* src = emb + (size_t)toks[a_r] * EMBED + kt * 64 + a_c;
            float4 va[8];
#pragma unroll
            for (int i = 0; i < 8; ++i) va[i] = *(const float4*)(src + i * 4);
#pragma unroll
            for (int i = 0; i < 4; ++i) {
                unsigned short h8[8];
#pragma unroll
                for (int e = 0; e < 8; ++e)
                    h8[e] = f16_bits(((const float*)&va[2 * i])[e]);   // va[2i],va[2i+1] contiguous
                *(s16x8*)(&As[swz_e(a_r, a_c + i * 8)]) = *(const s16x8*)h8;
            }
        }
        // ---- stage B: W rows -> fp16, reg transpose, swizzled ----
        {
            float4 rawB[8];
#pragma unroll
            for (int i = 0; i < 8; ++i)
                rawB[i] = *(const float4*)(W + (size_t)(kt * 64 + b_kb + i) * GATES + n0 + b_nb4);
#pragma unroll
            for (int nn = 0; nn < 4; ++nn) {
                unsigned short h8[8];
#pragma unroll
                for (int i = 0; i < 8; ++i)
                    h8[i] = f16_bits(((const float*)&rawB[i])[nn]);
                *(s16x8*)(&Bs[swz_e(b_nb4 + nn, b_kb)]) = *(const s16x8*)h8;
            }
        }
        __syncthreads();
        // ---- MFMA: 2 k-slices x 4x4 frags ----
#pragma unroll
        for (int ks = 0; ks < 2; ++ks) {
            const int kofs = ks * 32 + kg * 8;
            f16x8 av[4], bv[4];
#pragma unroll
            for (int mi = 0; mi < 4; ++mi)
                av[mi] = *(const f16x8*)(&As[swz_e(wm + mi * 16 + lr, kofs)]);
#pragma unroll
            for (int ni = 0; ni < 4; ++ni)
                bv[ni] = *(const f16x8*)(&Bs[swz_e(wn + ni * 16 + lr, kofs)]);
#pragma unroll
            for (int mi = 0; mi < 4; ++mi)
#pragma unroll
                for (int ni = 0; ni < 4; ++ni)
                    acc[mi][ni] = __builtin_amdgcn_mfma_f32_16x16x32_f16(av[mi], bv[ni], acc[mi][ni], 0, 0, 0);
        }
    }

    // ---- epilogue (r3 C/D convention): row = kg*4+r, col = lr ----
    float bcv[4];
#pragma unroll
    for (int ni = 0; ni < 4; ++ni) bcv[ni] = bias[n0 + wn + ni * 16 + lr];
#pragma unroll
    for (int mi = 0; mi < 4; ++mi) {
#pragma unroll
        for (int ni = 0; ni < 4; ++ni) {
#pragma unroll
            for (int r = 0; r < 4; ++r) {
                int m   = mt * 128 + wm + mi * 16 + kg * 4 + r;   // = t*16+b
                int col = n0 + wn + ni * 16 + lr;
                xWb[(size_t)m * GATES + col] = acc[mi][ni][r] + bcv[ni];
            }
        }
    }
}

// ---------- K2: FUSED, 512 threads (8 waves) — byte-identical to r22 -------
__global__ void __launch_bounds__(512, 2) k_fused(
    const unsigned short* __restrict__ ub_hi,
    const unsigned short* __restrict__ ub_lo,
    const float* __restrict__ xWb,
    unsigned short* __restrict__ hsl,
    const float* __restrict__ Wc,
    const float* __restrict__ bc,
    float* __restrict__ out) {
    __shared__ __align__(16) char smem_raw[32768];
    const int tid  = threadIdx.x;
    const int lane = tid & 63;
    const int w    = tid >> 6;            // wave 0..7

    if (blockIdx.x < NB) {
        // ================= recurrence path (h = fp16 hi ONLY) ==============
        __builtin_amdgcn_s_setprio(1);
        float (*zpart)[4][256] = (float (*)[4][256])smem_raw;  // [8][4][256] 32KB
        const int bid = blockIdx.x;
        const int j0  = bid * 16;

        const int b_own  = (tid >> 4) & 15;    // owners are tid<256
        const int jj_own = tid & 15;
        const int j_own  = j0 + jj_own;
        const int hb_e = ((j_own >> 5) * 512) + (((j_own >> 3) & 3) * 16 + b_own) * 8 + (j_own & 7);
        float c_own = 0.f;

        // preload U fragments (once): 4 gc-tiles x 4 kt per wave = 128 VGPR
        f16x8 Uh[4][4], Ul[4][4];
#pragma unroll
        for (int g = 0; g < 4; ++g)
#pragma unroll
            for (int q = 0; q < 4; ++q) {
                size_t o = (((size_t)(g * 64 + bid) * 32) + (w * 4 + q)) * 512 + lane * 8;
                Uh[g][q] = *(const f16x8*)(ub_hi + o);
                Ul[g][q] = *(const f16x8*)(ub_lo + o);
            }

        for (int t = 0; t < SEQ; ++t) {
            float xw0 = 0.f, xw1 = 0.f, xw2 = 0.f, xw3 = 0.f;
            if (tid < 256) {
                const float* xwp = xWb + ((size_t)t * BATCH + b_own) * GATES + j_own;
                xw0 = xwp[0]; xw1 = xwp[UNITS]; xw2 = xwp[2 * UNITS]; xw3 = xwp[3 * UNITS];
            }

            const unsigned long long* p64 =
                (const unsigned long long*)(hsl + (size_t)t * 32768);

            // ---- merged poll (hi plane only): detecting load IS data load --
            union HU { unsigned long long q2[2]; f16x8 v; };
            HU hh[4];
            while (true) {
                unsigned bad = 0;
#pragma unroll
                for (int q = 0; q < 4; ++q) {
                    const size_t u = (size_t)(w * 4 + q) * 128 + lane * 2;
                    hh[q].q2[0] = ld_u64(p64 + u);
                    hh[q].q2[1] = ld_u64(p64 + u + 1);
                }
#pragma unroll
                for (int q = 0; q < 4; ++q)
                    bad |= poison_u64(hh[q].q2[0]) | poison_u64(hh[q].q2[1]);
                if (__all((int)(bad == 0))) break;
                __builtin_amdgcn_s_sleep(2);
            }

            f32x4 a0[4], a1[4];
#pragma unroll
            for (int g = 0; g < 4; ++g) {
                a0[g] = (f32x4){0.f, 0.f, 0.f, 0.f};
                a1[g] = (f32x4){0.f, 0.f, 0.f, 0.f};
            }
#pragma unroll
            for (int q = 0; q < 4; ++q)
#pragma unroll
                for (int g = 0; g < 4; ++g) {
                    a0[g] = __builtin_amdgcn_mfma_f32_16x16x32_f16(hh[q].v, Uh[g][q], a0[g], 0, 0, 0);
                    a1[g] = __builtin_amdgcn_mfma_f32_16x16x32_f16(hh[q].v, Ul[g][q], a1[g], 0, 0, 0);
                }

            // single-buffer zpart, ONE barrier (dataflow implies write-order)
#pragma unroll
            for (int g = 0; g < 4; ++g)
#pragma unroll
                for (int r = 0; r < 4; ++r)
                    zpart[w][g][((lane >> 4) * 4 + r) * 16 + (lane & 15)] =
                        a0[g][r] + a1[g][r];
            __syncthreads();

            if (tid < 256) {
                const int zi_idx = b_own * 16 + jj_own;
                float zi = xw0, zf = xw1, zg = xw2, zo = xw3;
#pragma unroll
                for (int ww = 0; ww < 8; ++ww) {
                    zi += zpart[ww][0][zi_idx];
                    zf += zpart[ww][1][zi_idx];
                    zg += zpart[ww][2][zi_idx];
                    zo += zpart[ww][3][zi_idx];
                }
                float si = 1.f / (1.f + expf(-zi));
                float sf = 1.f / (1.f + expf(-zf));
                float so = 1.f / (1.f + expf(-zo));
                float c_new = sf * c_own + si * tanhf(zg);
                float h_new = so * tanhf(c_new);
                c_own = c_new;

                int hhi = (int)f16_bits(h_new);
                int hhi_nb = __shfl_xor(hhi, 1);
                unsigned short* nh = hsl + (size_t)(t + 1) * 32768;
                if ((tid & 1) == 0) {   // jj even -> adjacent pair 4B-aligned
                    unsigned hp = (unsigned)(unsigned short)hhi | ((unsigned)(unsigned short)hhi_nb << 16);
                    __hip_atomic_store((unsigned*)(nh + hb_e), hp,
                                       __ATOMIC_RELAXED, __HIP_MEMORY_SCOPE_AGENT);
                }
            }
            // no trailing barrier: next step's poll provides ordering.
        }
        return;
    }

    // ================= projection path (8-wave, mt2-major) =================
    // A = h hi ONLY (fp16 RNE of h).
    unsigned short* Bs = (unsigned short*)smem_raw;   // fp16 bits, 16 KB
    const int bidp = blockIdx.x - NB;                 // 0..3999
    const int mt2 = bidp / 250;                       // t-group, ASCENDING
    const int nt  = bidp % 250;
    const int n0 = nt * 128;

    // ---- gate on slot (mt2*8+8) hi plane fully non-poison ----
    {
        const unsigned long long* gp =
            (const unsigned long long*)(hsl + (size_t)(mt2 * 8 + 8) * 32768);
        {
            const unsigned long long* sp = gp + (size_t)tid * 8;   // 512*8=4096
            unsigned long long v = ld_u64(sp);
            while (poison_u64(v)) {
                __builtin_amdgcn_s_sleep(32);
                v = ld_u64(sp);
            }
        }
        while (true) {
            unsigned bad = 0;
#pragma unroll
            for (int i = 0; i < 8; ++i)
                bad |= poison_u64(ld_u64(gp + (size_t)i * 512 + tid));
            if (__syncthreads_and((int)(bad == 0))) break;
            __builtin_amdgcn_s_sleep(16);
        }
        asm volatile("" ::: "memory");
    }

    // wave split: wmt = (w>>2)*4 t-rows, wn = (w&3)*32 n-cols
    const int b_kb  = (tid >> 5) * 8;     // staging coords (tid<256 only)
    const int b_nb4 = (tid & 31) * 4;
    const int wmt  = (w >> 2) * 4;
    const int wn   = (w & 3) * 32;
    const int lr   = lane & 15;
    const int kg   = lane >> 4;

    f32x4 acc[4][2];                      // [mi -> t][ni]
#pragma unroll
    for (int i = 0; i < 4; ++i)
#pragma unroll
        for (int j = 0; j < 2; ++j) acc[i][j] = (f32x4){0.f, 0.f, 0.f, 0.f};

    const unsigned short* aslot[4];
#pragma unroll
    for (int mi = 0; mi < 4; ++mi)
        aslot[mi] = hsl + (size_t)(mt2 * 8 + wmt + mi + 1) * 32768 + lane * 8;

    f16x8 A0h[4], A1h[4];
#pragma unroll
    for (int mi = 0; mi < 4; ++mi) {
        A0h[mi] = *(const f16x8*)(aslot[mi]);
        A1h[mi] = *(const f16x8*)(aslot[mi] + 512);
    }
    float4 rawB[8];
    if (tid < 256) {
#pragma unroll
        for (int i = 0; i < 8; ++i)
            rawB[i] = *(const float4*)(Wc + (size_t)(b_kb + i) * VOCAB + n0 + b_nb4);
    }

    for (int kt = 0; kt < 16; ++kt) {
        __syncthreads();
        if (tid < 256) {
#pragma unroll
            for (int nn = 0; nn < 4; ++nn) {
                unsigned short h8[8];
#pragma unroll
                for (int i = 0; i < 8; ++i)
                    h8[i] = f16_bits(((const float*)&rawB[i])[nn]);
                int e = swz_e(b_nb4 + nn, b_kb);
                *(s16x8*)(&Bs[e]) = *(const s16x8*)h8;
            }
        }
        __syncthreads();
        if (kt < 15 && tid < 256) {
            const int k0n = (kt + 1) * 64;
#pragma unroll
            for (int i = 0; i < 8; ++i)
                rawB[i] = *(const float4*)(Wc + (size_t)(k0n + b_kb + i) * VOCAB + n0 + b_nb4);
        }
        // ks = 0
        {
            f16x8 bh[2];
#pragma unroll
            for (int ni = 0; ni < 2; ++ni)
                bh[ni] = *(const f16x8*)(&Bs[swz_e(wn + ni * 16 + lr, kg * 8)]);
#pragma unroll
            for (int mi = 0; mi < 4; ++mi)
#pragma unroll
                for (int ni = 0; ni < 2; ++ni)
                    acc[mi][ni] = __builtin_amdgcn_mfma_f32_16x16x32_f16(A0h[mi], bh[ni], acc[mi][ni], 0, 0, 0);
            if (kt < 15) {
                const int base = (kt + 1) * 1024;
#pragma unroll
                for (int mi = 0; mi < 4; ++mi)
                    A0h[mi] = *(const f16x8*)(aslot[mi] + base);
            }
        }
        // ks = 1
        {
            f16x8 bh[2];
#pragma unroll
            for (int ni = 0; ni < 2; ++ni)
                bh[ni] = *(const f16x8*)(&Bs[swz_e(wn + ni * 16 + lr, 32 + kg * 8)]);
#pragma unroll
            for (int mi = 0; mi < 4; ++mi)
#pragma unroll
                for (int ni = 0; ni < 2; ++ni)
                    acc[mi][ni] = __builtin_amdgcn_mfma_f32_16x16x32_f16(A1h[mi], bh[ni], acc[mi][ni], 0, 0, 0);
            if (kt < 15) {
                const int base = (kt + 1) * 1024 + 512;
#pragma unroll
                for (int mi = 0; mi < 4; ++mi)
                    A1h[mi] = *(const f16x8*)(aslot[mi] + base);
            }
        }
    }

    // ---- epilogue: nontemporal stores (out never re-read; keep L3 for Wc/h)
    float bcv[2];
#pragma unroll
    for (int ni = 0; ni < 2; ++ni) bcv[ni] = bc[n0 + wn + ni * 16 + lr];
#pragma unroll
    for (int mi = 0; mi < 4; ++mi) {
        const int trow = mt2 * 8 + wmt + mi;
#pragma unroll
        for (int ni = 0; ni < 2; ++ni) {
#pragma unroll
            for (int r = 0; r < 4; ++r) {
                int grow = (kg * 4 + r) * 128 + trow;     // m = b*128 + t
                int gcol = n0 + wn + ni * 16 + lr;
                __builtin_nontemporal_store(acc[mi][ni][r] + bcv[ni],
                                            &out[(size_t)grow * VOCAB + gcol]);
            }
        }
    }
}

extern "C" void kernel_launch(void* const* d_in, const int* in_sizes, int n_in,
                              void* d_out, int out_size, void* d_ws, size_t ws_size,
                              hipStream_t stream) {
    const int*   inputs = (const int*)d_in[0];   // int32 (JAX x64 disabled)
    const float* emb  = (const float*)d_in[1];
    const float* W    = (const float*)d_in[2];
    const float* U    = (const float*)d_in[3];
    const float* bias = (const float*)d_in[4];
    const float* Wc   = (const float*)d_in[5];
    const float* bc   = (const float*)d_in[6];
    float* out = (float*)d_out;

    char* ws = (char*)d_ws;
    float*          xWb   = (float*)(ws + 0);
    unsigned short* ub_hi = (unsigned short*)(ws + 33554432);
    unsigned short* ub_lo = (unsigned short*)(ws + 41943040);
    unsigned short* hsl   = (unsigned short*)(ws + 50331648);

    // slot 0 = h0 = 0 (valid); slots 1..128 poisoned 0xFFFF — every call
    hipMemsetAsync(hsl, 0, 65536, stream);
    hipMemsetAsync((char*)hsl + 65536, 0xFF, 8454144 - 65536, stream);

    k_prep<<<256 + 512, 256, 0, stream>>>(U, ub_hi, ub_lo,
                                          inputs, emb, W, bias, xWb);
    k_fused<<<NB + 4000, 512, 0, stream>>>(ub_hi, ub_lo, xWb, hsl, Wc, bc, out);
}

// Round 24
// 592.443 us; speedup vs baseline: 1.2497x; 1.0008x over previous
//
#include <hip/hip_runtime.h>
#include <hip/hip_bf16.h>
#include <math.h>

// LSTM language model. Round 24: r23 config (best: 593us) with ONE isolated
// delta — activations use hardware exp (v_exp_f32 via __expf) instead of
// libm expf/tanhf: ~150 serial VALU ops on the 128-hop critical chain -> ~10.
// sigmoid(x)=1/(1+__expf(-x)); tanh(x)=1-2/(__expf(2x)+1) (saturates right).
// ws layout (~58.8 MB):
//   xWb    [128][16][4096] f32      33,554,432 B @ 0
//   ub_hi  [256ct][32kt][64][8] f16  8,388,608 B @ 33,554,432
//   ub_lo   (same)                   8,388,608 B @ 41,943,040
//   hslots [129][hi 16384 | lo 16384] ushort = 8,454,144 B @ 50,331,648
//          (lo plane unused); slot 0 zeroed (h0), rest poisoned 0xFFFF.

#define VOCAB 32000
#define EMBED 256
#define UNITS 1024
#define GATES 4096
#define BATCH 16
#define SEQ 128
#define NB 64   // persistent recurrence blocks (16 cells each, 512 thr)

using s16x8 = __attribute__((ext_vector_type(8))) short;
using f16x8 = __attribute__((ext_vector_type(8))) _Float16;
using f32x4 = __attribute__((ext_vector_type(4))) float;

__device__ __forceinline__ unsigned short f16_bits(float x) {
    _Float16 h = (_Float16)x;                 // v_cvt_f16_f32, RNE
    return __builtin_bit_cast(unsigned short, h);
}
__device__ __forceinline__ float f16_f32(unsigned short b) {
    return (float)__builtin_bit_cast(_Float16, b);
}
__device__ __forceinline__ int swz_e(int r, int k) {
    return (r * 64 + k) ^ ((((r & 7) ^ ((r >> 2) & 7))) << 3);
}
__device__ __forceinline__ unsigned long long ld_u64(const unsigned long long* p) {
    return __hip_atomic_load(p, __ATOMIC_RELAXED, __HIP_MEMORY_SCOPE_AGENT);
}
__device__ __forceinline__ unsigned poison_u64(unsigned long long v) {
    return (unsigned)((unsigned)v == 0xFFFFFFFFu) |
           (unsigned)((unsigned)(v >> 32) == 0xFFFFFFFFu);
}
__device__ __forceinline__ float fast_sigmoid(float x) {
    return 1.f / (1.f + __expf(-x));
}
__device__ __forceinline__ float fast_tanh(float x) {
    return 1.f - 2.f / (__expf(2.f * x) + 1.f);
}

// ---------- K0: merged prep — blocks 0..255: U -> fp16 hi/lo fragments;
// blocks 256..767: xWb = emb@W + bias via fp16 MFMA GEMM (r3 tile) ----------
__global__ void __launch_bounds__(256) k_prep(
    const float* __restrict__ U,
    unsigned short* __restrict__ ub_hi,
    unsigned short* __restrict__ ub_lo,
    const int* __restrict__ inputs,
    const float* __restrict__ emb,
    const float* __restrict__ W,
    const float* __restrict__ bias,
    float* __restrict__ xWb) {
    __shared__ __align__(16) char smem_raw[65536];
    const int tid = threadIdx.x;

    if (blockIdx.x < 256) {
        // ---- U conversion (r13 layout) ----
        float* lds_u = (float*)smem_raw;       // [k][16 cols], 64 KB
        const int ct = blockIdx.x;
        for (int k = tid; k < 1024; k += 256) {
            const float4* src = (const float4*)(U + (size_t)k * GATES + ct * 16);
            float4* dst = (float4*)(&lds_u[k * 16]);
            dst[0] = src[0]; dst[1] = src[1]; dst[2] = src[2]; dst[3] = src[3];
        }
        __syncthreads();
        const int lane = tid & 63;
        const int coll = lane & 15;
        const int kg = lane >> 4;
        for (int kt = (tid >> 6); kt < 32; kt += 4) {
            const int ks = kt * 32 + kg * 8;
            unsigned short h8[8], l8[8];
#pragma unroll
            for (int e = 0; e < 8; ++e) {
                float v = lds_u[(ks + e) * 16 + coll];
                unsigned short hb = f16_bits(v);
                h8[e] = hb;
                l8[e] = f16_bits(v - f16_f32(hb));
            }
            size_t o = (((size_t)ct * 32 + kt) * 64 + lane) * 8;
            *(s16x8*)(ub_hi + o) = *(const s16x8*)h8;
            *(s16x8*)(ub_lo + o) = *(const s16x8*)l8;
        }
        return;
    }

    // ---- xW GEMM: m = t*16+b (2048 rows), n = 4096 cols, K = 256 ----
    unsigned short* As = (unsigned short*)smem_raw;            // [128][64] swz
    unsigned short* Bs = (unsigned short*)(smem_raw + 16384);  // [128][64] swz
    int* toks = (int*)(smem_raw + 32768);                      // [128]
    const int bid2 = blockIdx.x - 256;
    const int mt = bid2 & 15;
    const int nt = bid2 >> 4;
    const int n0 = nt * 128;

    const int lane = tid & 63;
    const int w4   = tid >> 6;
    const int wm   = (w4 >> 1) * 64;
    const int wn   = (w4 & 1) * 64;
    const int lr   = lane & 15;
    const int kg   = lane >> 4;

    if (tid < 128) {
        const int m = mt * 128 + tid;
        toks[tid] = inputs[(m & 15) * SEQ + (m >> 4)];   // b*SEQ + t
    }

    f32x4 acc[4][4];
#pragma unroll
    for (int i = 0; i < 4; ++i)
#pragma unroll
        for (int j = 0; j < 4; ++j) acc[i][j] = (f32x4){0.f, 0.f, 0.f, 0.f};

    const int a_r = tid >> 1;              // A row 0..127
    const int a_c = (tid & 1) * 32;        // k-offset within 64
    const int b_kb  = (tid >> 5) * 8;
    const int b_nb4 = (tid & 31) * 4;

    for (int kt = 0; kt < 4; ++kt) {
        __syncthreads();   // prior frag reads done; kt=0: toks visible
        // ---- stage A: emb rows -> fp16, swizzled (32 f32/thread) ----
        {
            const float* src = emb + (size_t)toks[a_r] * EMBED + kt * 64 + a_c;
            float4 va[8];
#pragma unroll
            for (int i = 0; i < 8; ++i) va[i] = *(const float4*)(src + i * 4);
#pragma unroll
            for (int i = 0; i < 4; ++i) {
                unsigned short h8[8];
#pragma unroll
                for (int e = 0; e < 8; ++e)
                    h8[e] = f16_bits(((const float*)&va[2 * i])[e]);
                *(s16x8*)(&As[swz_e(a_r, a_c + i * 8)]) = *(const s16x8*)h8;
            }
        }
        // ---- stage B: W rows -> fp16, reg transpose, swizzled ----
        {
            float4 rawB[8];
#pragma unroll
            for (int i = 0; i < 8; ++i)
                rawB[i] = *(const float4*)(W + (size_t)(kt * 64 + b_kb + i) * GATES + n0 + b_nb4);
#pragma unroll
            for (int nn = 0; nn < 4; ++nn) {
                unsigned short h8[8];
#pragma unroll
                for (int i = 0; i < 8; ++i)
                    h8[i] = f16_bits(((const float*)&rawB[i])[nn]);
                *(s16x8*)(&Bs[swz_e(b_nb4 + nn, b_kb)]) = *(const s16x8*)h8;
            }
        }
        __syncthreads();
        // ---- MFMA: 2 k-slices x 4x4 frags ----
#pragma unroll
        for (int ks = 0; ks < 2; ++ks) {
            const int kofs = ks * 32 + kg * 8;
            f16x8 av[4], bv[4];
#pragma unroll
            for (int mi = 0; mi < 4; ++mi)
                av[mi] = *(const f16x8*)(&As[swz_e(wm + mi * 16 + lr, kofs)]);
#pragma unroll
            for (int ni = 0; ni < 4; ++ni)
                bv[ni] = *(const f16x8*)(&Bs[swz_e(wn + ni * 16 + lr, kofs)]);
#pragma unroll
            for (int mi = 0; mi < 4; ++mi)
#pragma unroll
                for (int ni = 0; ni < 4; ++ni)
                    acc[mi][ni] = __builtin_amdgcn_mfma_f32_16x16x32_f16(av[mi], bv[ni], acc[mi][ni], 0, 0, 0);
        }
    }

    // ---- epilogue: row = kg*4+r, col = lr ----
    float bcv[4];
#pragma unroll
    for (int ni = 0; ni < 4; ++ni) bcv[ni] = bias[n0 + wn + ni * 16 + lr];
#pragma unroll
    for (int mi = 0; mi < 4; ++mi) {
#pragma unroll
        for (int ni = 0; ni < 4; ++ni) {
#pragma unroll
            for (int r = 0; r < 4; ++r) {
                int m   = mt * 128 + wm + mi * 16 + kg * 4 + r;   // = t*16+b
                int col = n0 + wn + ni * 16 + lr;
                xWb[(size_t)m * GATES + col] = acc[mi][ni][r] + bcv[ni];
            }
        }
    }
}

// ---------- K2: FUSED, 512 threads (8 waves) -------------------------------
__global__ void __launch_bounds__(512, 2) k_fused(
    const unsigned short* __restrict__ ub_hi,
    const unsigned short* __restrict__ ub_lo,
    const float* __restrict__ xWb,
    unsigned short* __restrict__ hsl,
    const float* __restrict__ Wc,
    const float* __restrict__ bc,
    float* __restrict__ out) {
    __shared__ __align__(16) char smem_raw[32768];
    const int tid  = threadIdx.x;
    const int lane = tid & 63;
    const int w    = tid >> 6;            // wave 0..7

    if (blockIdx.x < NB) {
        // ================= recurrence path (h = fp16 hi ONLY) ==============
        __builtin_amdgcn_s_setprio(1);
        float (*zpart)[4][256] = (float (*)[4][256])smem_raw;  // [8][4][256] 32KB
        const int bid = blockIdx.x;
        const int j0  = bid * 16;

        const int b_own  = (tid >> 4) & 15;    // owners are tid<256
        const int jj_own = tid & 15;
        const int j_own  = j0 + jj_own;
        const int hb_e = ((j_own >> 5) * 512) + (((j_own >> 3) & 3) * 16 + b_own) * 8 + (j_own & 7);
        float c_own = 0.f;

        // preload U fragments (once): 4 gc-tiles x 4 kt per wave = 128 VGPR
        f16x8 Uh[4][4], Ul[4][4];
#pragma unroll
        for (int g = 0; g < 4; ++g)
#pragma unroll
            for (int q = 0; q < 4; ++q) {
                size_t o = (((size_t)(g * 64 + bid) * 32) + (w * 4 + q)) * 512 + lane * 8;
                Uh[g][q] = *(const f16x8*)(ub_hi + o);
                Ul[g][q] = *(const f16x8*)(ub_lo + o);
            }

        for (int t = 0; t < SEQ; ++t) {
            float xw0 = 0.f, xw1 = 0.f, xw2 = 0.f, xw3 = 0.f;
            if (tid < 256) {
                const float* xwp = xWb + ((size_t)t * BATCH + b_own) * GATES + j_own;
                xw0 = xwp[0]; xw1 = xwp[UNITS]; xw2 = xwp[2 * UNITS]; xw3 = xwp[3 * UNITS];
            }

            const unsigned long long* p64 =
                (const unsigned long long*)(hsl + (size_t)t * 32768);

            // ---- merged poll (hi plane only): detecting load IS data load --
            union HU { unsigned long long q2[2]; f16x8 v; };
            HU hh[4];
            while (true) {
                unsigned bad = 0;
#pragma unroll
                for (int q = 0; q < 4; ++q) {
                    const size_t u = (size_t)(w * 4 + q) * 128 + lane * 2;
                    hh[q].q2[0] = ld_u64(p64 + u);
                    hh[q].q2[1] = ld_u64(p64 + u + 1);
                }
#pragma unroll
                for (int q = 0; q < 4; ++q)
                    bad |= poison_u64(hh[q].q2[0]) | poison_u64(hh[q].q2[1]);
                if (__all((int)(bad == 0))) break;
                __builtin_amdgcn_s_sleep(2);
            }

            f32x4 a0[4], a1[4];
#pragma unroll
            for (int g = 0; g < 4; ++g) {
                a0[g] = (f32x4){0.f, 0.f, 0.f, 0.f};
                a1[g] = (f32x4){0.f, 0.f, 0.f, 0.f};
            }
#pragma unroll
            for (int q = 0; q < 4; ++q)
#pragma unroll
                for (int g = 0; g < 4; ++g) {
                    a0[g] = __builtin_amdgcn_mfma_f32_16x16x32_f16(hh[q].v, Uh[g][q], a0[g], 0, 0, 0);
                    a1[g] = __builtin_amdgcn_mfma_f32_16x16x32_f16(hh[q].v, Ul[g][q], a1[g], 0, 0, 0);
                }

            // single-buffer zpart, ONE barrier (dataflow implies write-order)
#pragma unroll
            for (int g = 0; g < 4; ++g)
#pragma unroll
                for (int r = 0; r < 4; ++r)
                    zpart[w][g][((lane >> 4) * 4 + r) * 16 + (lane & 15)] =
                        a0[g][r] + a1[g][r];
            __syncthreads();

            if (tid < 256) {
                const int zi_idx = b_own * 16 + jj_own;
                float zi = xw0, zf = xw1, zg = xw2, zo = xw3;
#pragma unroll
                for (int ww = 0; ww < 8; ++ww) {
                    zi += zpart[ww][0][zi_idx];
                    zf += zpart[ww][1][zi_idx];
                    zg += zpart[ww][2][zi_idx];
                    zo += zpart[ww][3][zi_idx];
                }
                float si = fast_sigmoid(zi);
                float sf = fast_sigmoid(zf);
                float so = fast_sigmoid(zo);
                float c_new = sf * c_own + si * fast_tanh(zg);
                float h_new = so * fast_tanh(c_new);
                c_own = c_new;

                int hhi = (int)f16_bits(h_new);
                int hhi_nb = __shfl_xor(hhi, 1);
                unsigned short* nh = hsl + (size_t)(t + 1) * 32768;
                if ((tid & 1) == 0) {   // jj even -> adjacent pair 4B-aligned
                    unsigned hp = (unsigned)(unsigned short)hhi | ((unsigned)(unsigned short)hhi_nb << 16);
                    __hip_atomic_store((unsigned*)(nh + hb_e), hp,
                                       __ATOMIC_RELAXED, __HIP_MEMORY_SCOPE_AGENT);
                }
            }
            // no trailing barrier: next step's poll provides ordering.
        }
        return;
    }

    // ================= projection path (8-wave, mt2-major) =================
    // A = h hi ONLY (fp16 RNE of h).
    unsigned short* Bs = (unsigned short*)smem_raw;   // fp16 bits, 16 KB
    const int bidp = blockIdx.x - NB;                 // 0..3999
    const int mt2 = bidp / 250;                       // t-group, ASCENDING
    const int nt  = bidp % 250;
    const int n0 = nt * 128;

    // ---- gate on slot (mt2*8+8) hi plane fully non-poison ----
    {
        const unsigned long long* gp =
            (const unsigned long long*)(hsl + (size_t)(mt2 * 8 + 8) * 32768);
        {
            const unsigned long long* sp = gp + (size_t)tid * 8;   // 512*8=4096
            unsigned long long v = ld_u64(sp);
            while (poison_u64(v)) {
                __builtin_amdgcn_s_sleep(32);
                v = ld_u64(sp);
            }
        }
        while (true) {
            unsigned bad = 0;
#pragma unroll
            for (int i = 0; i < 8; ++i)
                bad |= poison_u64(ld_u64(gp + (size_t)i * 512 + tid));
            if (__syncthreads_and((int)(bad == 0))) break;
            __builtin_amdgcn_s_sleep(16);
        }
        asm volatile("" ::: "memory");
    }

    // wave split: wmt = (w>>2)*4 t-rows, wn = (w&3)*32 n-cols
    const int b_kb  = (tid >> 5) * 8;     // staging coords (tid<256 only)
    const int b_nb4 = (tid & 31) * 4;
    const int wmt  = (w >> 2) * 4;
    const int wn   = (w & 3) * 32;
    const int lr   = lane & 15;
    const int kg   = lane >> 4;

    f32x4 acc[4][2];                      // [mi -> t][ni]
#pragma unroll
    for (int i = 0; i < 4; ++i)
#pragma unroll
        for (int j = 0; j < 2; ++j) acc[i][j] = (f32x4){0.f, 0.f, 0.f, 0.f};

    const unsigned short* aslot[4];
#pragma unroll
    for (int mi = 0; mi < 4; ++mi)
        aslot[mi] = hsl + (size_t)(mt2 * 8 + wmt + mi + 1) * 32768 + lane * 8;

    f16x8 A0h[4], A1h[4];
#pragma unroll
    for (int mi = 0; mi < 4; ++mi) {
        A0h[mi] = *(const f16x8*)(aslot[mi]);
        A1h[mi] = *(const f16x8*)(aslot[mi] + 512);
    }
    float4 rawB[8];
    if (tid < 256) {
#pragma unroll
        for (int i = 0; i < 8; ++i)
            rawB[i] = *(const float4*)(Wc + (size_t)(b_kb + i) * VOCAB + n0 + b_nb4);
    }

    for (int kt = 0; kt < 16; ++kt) {
        __syncthreads();
        if (tid < 256) {
#pragma unroll
            for (int nn = 0; nn < 4; ++nn) {
                unsigned short h8[8];
#pragma unroll
                for (int i = 0; i < 8; ++i)
                    h8[i] = f16_bits(((const float*)&rawB[i])[nn]);
                int e = swz_e(b_nb4 + nn, b_kb);
                *(s16x8*)(&Bs[e]) = *(const s16x8*)h8;
            }
        }
        __syncthreads();
        if (kt < 15 && tid < 256) {
            const int k0n = (kt + 1) * 64;
#pragma unroll
            for (int i = 0; i < 8; ++i)
                rawB[i] = *(const float4*)(Wc + (size_t)(k0n + b_kb + i) * VOCAB + n0 + b_nb4);
        }
        // ks = 0
        {
            f16x8 bh[2];
#pragma unroll
            for (int ni = 0; ni < 2; ++ni)
                bh[ni] = *(const f16x8*)(&Bs[swz_e(wn + ni * 16 + lr, kg * 8)]);
#pragma unroll
            for (int mi = 0; mi < 4; ++mi)
#pragma unroll
                for (int ni = 0; ni < 2; ++ni)
                    acc[mi][ni] = __builtin_amdgcn_mfma_f32_16x16x32_f16(A0h[mi], bh[ni], acc[mi][ni], 0, 0, 0);
            if (kt < 15) {
                const int base = (kt + 1) * 1024;
#pragma unroll
                for (int mi = 0; mi < 4; ++mi)
                    A0h[mi] = *(const f16x8*)(aslot[mi] + base);
            }
        }
        // ks = 1
        {
            f16x8 bh[2];
#pragma unroll
            for (int ni = 0; ni < 2; ++ni)
                bh[ni] = *(const f16x8*)(&Bs[swz_e(wn + ni * 16 + lr, 32 + kg * 8)]);
#pragma unroll
            for (int mi = 0; mi < 4; ++mi)
#pragma unroll
                for (int ni = 0; ni < 2; ++ni)
                    acc[mi][ni] = __builtin_amdgcn_mfma_f32_16x16x32_f16(A1h[mi], bh[ni], acc[mi][ni], 0, 0, 0);
            if (kt < 15) {
                const int base = (kt + 1) * 1024 + 512;
#pragma unroll
                for (int mi = 0; mi < 4; ++mi)
                    A1h[mi] = *(const f16x8*)(aslot[mi] + base);
            }
        }
    }

    // ---- epilogue: nontemporal stores (out never re-read; keep L3 for Wc/h)
    float bcv[2];
#pragma unroll
    for (int ni = 0; ni < 2; ++ni) bcv[ni] = bc[n0 + wn + ni * 16 + lr];
#pragma unroll
    for (int mi = 0; mi < 4; ++mi) {
        const int trow = mt2 * 8 + wmt + mi;
#pragma unroll
        for (int ni = 0; ni < 2; ++ni) {
#pragma unroll
            for (int r = 0; r < 4; ++r) {
                int grow = (kg * 4 + r) * 128 + trow;     // m = b*128 + t
                int gcol = n0 + wn + ni * 16 + lr;
                __builtin_nontemporal_store(acc[mi][ni][r] + bcv[ni],
                                            &out[(size_t)grow * VOCAB + gcol]);
            }
        }
    }
}

extern "C" void kernel_launch(void* const* d_in, const int* in_sizes, int n_in,
                              void* d_out, int out_size, void* d_ws, size_t ws_size,
                              hipStream_t stream) {
    const int*   inputs = (const int*)d_in[0];   // int32 (JAX x64 disabled)
    const float* emb  = (const float*)d_in[1];
    const float* W    = (const float*)d_in[2];
    const float* U    = (const float*)d_in[3];
    const float* bias = (const float*)d_in[4];
    const float* Wc   = (const float*)d_in[5];
    const float* bc   = (const float*)d_in[6];
    float* out = (float*)d_out;

    char* ws = (char*)d_ws;
    float*          xWb   = (float*)(ws + 0);
    unsigned short* ub_hi = (unsigned short*)(ws + 33554432);
    unsigned short* ub_lo = (unsigned short*)(ws + 41943040);
    unsigned short* hsl   = (unsigned short*)(ws + 50331648);

    // slot 0 = h0 = 0 (valid); slots 1..128 poisoned 0xFFFF — every call
    hipMemsetAsync(hsl, 0, 65536, stream);
    hipMemsetAsync((char*)hsl + 65536, 0xFF, 8454144 - 65536, stream);

    k_prep<<<256 + 512, 256, 0, stream>>>(U, ub_hi, ub_lo,
                                          inputs, emb, W, bias, xWb);
    k_fused<<<NB + 4000, 512, 0, stream>>>(ub_hi, ub_lo, xWb, hsl, Wc, bc, out);
}